// Round 1
// baseline (3383.513 us; speedup 1.0000x reference)
//
#include <hip/hip_runtime.h>
#include <hip/hip_bf16.h>

// DSSResNet on MI355X. Pipeline:
//  enc(fp32) -> [xform->bf16 swz] -> 3x { conv1(MFMA bf16,bn,relu) -> xform -> conv2(MFMA,bn,+res,relu) }
//  -> 4x { dss recurrence (fp32, fwd+bwd states per wave) -> fused GEMM+GLU+skip+LN }
//  -> dec(fp32)

#define BN   16
#define HCH  128
#define LSEQ 8192
#define NST  32
#define NLAY 4
#define XT_BSTRIDE 2101248ull   // 8208 rows (l=-4..8203) * 256 B per b

typedef __attribute__((ext_vector_type(4))) float f32x4;
typedef __attribute__((ext_vector_type(8))) short short8;
typedef unsigned short u16;
typedef unsigned int   u32;

struct __align__(8) U2 { u32 x, y; };

__device__ __forceinline__ u16 f2bf(float f){
  union { float f; u32 u; } v; v.f = f;
  u32 u = v.u;
  return (u16)((u + 0x7fffu + ((u >> 16) & 1u)) >> 16);   // RNE
}
__device__ __forceinline__ float geluf(float v){
  return 0.5f * v * (1.0f + erff(v * 0.70710678118654752f));
}

#define GLDS16(g, l) \
  __builtin_amdgcn_global_load_lds((const __attribute__((address_space(1))) u32*)(g), \
                                   (__attribute__((address_space(3))) u32*)(l), 16, 0, 0)

// ---------------- zero xTs halo rows (l=-4..-1, 8192..8203) ----------------
__global__ void k_xpad(u16* xTs){
  int b = blockIdx.x, t = threadIdx.x;
  char* base = (char*)xTs + (size_t)b * XT_BSTRIDE;
  int r = t >> 4;
  int row = (r < 4) ? r : (8196 + (r - 4));
  f32x4 z = {0.f, 0.f, 0.f, 0.f};
  *(f32x4*)(base + (size_t)row * 256 + (size_t)(t & 15) * 16) = z;
}

// ---------------- resnet weights -> bf16, K-major (k*128+ci), chunked+swizzled ----------------
// byte(conv,chunk,co,j) = conv*229376 + chunk*16384 + co*128 + ((j*2) ^ ((co&7)<<4))
__global__ void k_wxform(const float* __restrict__ w1, const float* __restrict__ w2, u16* __restrict__ wswz){
  int idx = blockIdx.x * 256 + threadIdx.x;
  if (idx >= 6 * 128 * 896) return;
  int conv = idx / (128 * 896);
  int rem  = idx % (128 * 896);
  int co = rem / 896, K = rem % 896;
  int k = K >> 7, ci = K & 127;
  const float* src = (conv & 1) ? w2 : w1;
  int blk = conv >> 1;
  float v = src[(((size_t)blk * 128 + co) * 128 + ci) * 7 + k];
  int chunk = K >> 6, j = K & 63;
  size_t byteoff = (size_t)conv * 229376 + (size_t)chunk * 16384 + (size_t)co * 128
                 + (u32)((j * 2) ^ ((co & 7) << 4));
  *(u16*)((char*)wswz + byteoff) = f2bf(v);
}

// ---------------- DSS per-layer params: r = exp(dt*Lam), Wc = W*(r-1)/Lam ----------------
// dssp layout per layer: [6][H][N] : 0 r_re, 1 r_im, 2 wc0_re, 3 wc0_im, 4 wc1_re, 5 wc1_im
__global__ void k_dssprep(const float* __restrict__ lam_re, const float* __restrict__ lam_im,
                          const float* __restrict__ log_dt, const float* __restrict__ W_re,
                          const float* __restrict__ W_im, float* __restrict__ dssp){
  int idx = blockIdx.x * 256 + threadIdx.x;
  if (idx >= NLAY * HCH * NST) return;
  int layer = idx / (HCH * NST);
  int hn = idx % (HCH * NST);
  int h = hn / NST, n = hn % NST;
  float Lre = -expf(lam_re[layer * NST + n]);
  float Lim = lam_im[layer * NST + n];
  float dt  = expf(log_dt[layer * HCH + h]);
  float are = dt * Lre, aim = dt * Lim;
  float er = expf(are);
  float rre = er * cosf(aim);
  float rim = er * sinf(aim);
  float nre = rre - 1.f, nim = rim;
  float den = 1.f / (Lre * Lre + Lim * Lim);
  float fre = (nre * Lre + nim * Lim) * den;
  float fim = (nim * Lre - nre * Lim) * den;
  float* base = dssp + (size_t)layer * 6 * HCH * NST;
  base[(0 * HCH + h) * NST + n] = rre;
  base[(1 * HCH + h) * NST + n] = rim;
  #pragma unroll
  for (int cc = 0; cc < 2; ++cc){
    float wr_ = W_re[(((size_t)layer * 2 + cc) * HCH + h) * NST + n];
    float wi_ = W_im[(((size_t)layer * 2 + cc) * HCH + h) * NST + n];
    base[((2 + 2 * cc) * HCH + h) * NST + n] = wr_ * fre - wi_ * fim;
    base[((3 + 2 * cc) * HCH + h) * NST + n] = wr_ * fim + wi_ * fre;
  }
}

// ---------------- encoder conv: (B,5,L) -> (B,128,L), K=15 'same', fp32 ----------------
__global__ __launch_bounds__(128) void k_enc(const float* __restrict__ xin, const float* __restrict__ w,
                                             const float* __restrict__ bias, float* __restrict__ X){
  int b = blockIdx.y, l0 = blockIdx.x * 64;
  int t = threadIdx.x;                       // t = co
  __shared__ float xs[5][78];
  for (int i = t; i < 5 * 78; i += 128){
    int ci = i / 78, j = i % 78;
    int l = l0 - 7 + j;
    xs[ci][j] = (l >= 0 && l < LSEQ) ? xin[((size_t)b * 5 + ci) * LSEQ + l] : 0.f;
  }
  float wreg[75];
  #pragma unroll
  for (int i = 0; i < 75; ++i) wreg[i] = w[t * 75 + i];
  float bc = bias[t];
  __syncthreads();
  size_t orow = ((size_t)b * HCH + t) * LSEQ + l0;
  for (int gb = 0; gb < 8; ++gb){
    float acc[8] = {0, 0, 0, 0, 0, 0, 0, 0};
    #pragma unroll
    for (int ci = 0; ci < 5; ++ci){
      #pragma unroll
      for (int k = 0; k < 15; ++k){
        float wv = wreg[ci * 15 + k];
        #pragma unroll
        for (int j = 0; j < 8; ++j)
          acc[j] = fmaf(wv, xs[ci][gb * 8 + j + k], acc[j]);
      }
    }
    f32x4 o0 = {acc[0] + bc, acc[1] + bc, acc[2] + bc, acc[3] + bc};
    f32x4 o1 = {acc[4] + bc, acc[5] + bc, acc[6] + bc, acc[7] + bc};
    *(f32x4*)&X[orow + gb * 8]     = o0;
    *(f32x4*)&X[orow + gb * 8 + 4] = o1;
  }
}

// ---------------- X (b,h,l) fp32 -> xTs (b,l,ci) bf16, row-swizzled by (l&7) ----------------
__global__ __launch_bounds__(256) void k_xform(const float* __restrict__ Xin, u16* __restrict__ xTs){
  int b = blockIdx.y, l0 = blockIdx.x * 64;
  int t = threadIdx.x;
  __shared__ float tile[128][65];
  #pragma unroll
  for (int it = 0; it < 32; ++it){
    int idx = t + it * 256;
    int ci = idx >> 6, j = idx & 63;
    tile[ci][j] = Xin[((size_t)b * HCH + ci) * LSEQ + l0 + j];
  }
  __syncthreads();
  int rl = t >> 2, q = t & 3;
  int l = l0 + rl;
  char* rowp = (char*)xTs + (size_t)b * XT_BSTRIDE + (size_t)(l + 4) * 256;
  u32 key = ((u32)l & 7u) << 4;
  #pragma unroll
  for (int ii = 0; ii < 8; ++ii){
    int c0 = q * 32 + ii * 4;
    U2 val;
    val.x = (u32)f2bf(tile[c0 + 0][rl]) | ((u32)f2bf(tile[c0 + 1][rl]) << 16);
    val.y = (u32)f2bf(tile[c0 + 2][rl]) | ((u32)f2bf(tile[c0 + 3][rl]) << 16);
    *(U2*)(rowp + (((u32)(c0 * 2)) ^ key)) = val;
  }
}

// ---------------- resnet conv (K=7) as MFMA GEMM: M=co128, N=l128-tile, K=896 ----------------
__global__ __launch_bounds__(256, 2) void k_conv(
    const u16* __restrict__ xTs, const u16* __restrict__ wcv,
    const float* __restrict__ bng, const float* __restrict__ bnb, const float* __restrict__ bnbe,
    const float* __restrict__ Xres, float* __restrict__ Xout)
{
  int b = blockIdx.y, l0 = blockIdx.x * 128;
  int tid = threadIdx.x, lane = tid & 63, wv = tid >> 6;
  int wr = wv >> 1, wc = wv & 1;
  int lan15 = lane & 15, lhi = lane >> 4;

  __shared__ alignas(16) u16 xt[144 * 128];      // 36864 B: rows l0-4 .. l0+139 (swizzled image)
  __shared__ alignas(16) u16 wch[2][128 * 64];   // 2 x 16384 B weight chunks

  const char* xsrc = (const char*)xTs + (size_t)b * XT_BSTRIDE + (size_t)l0 * 256;
  #pragma unroll
  for (int is = 0; is < 9; ++is){
    int off = is * 4096 + wv * 1024;
    GLDS16(xsrc + off + (lane << 4), (char*)xt + off);
  }
  {
    const char* wsrc = (const char*)wcv;
    #pragma unroll
    for (int is = 0; is < 4; ++is){
      int off = is * 4096 + wv * 1024;
      GLDS16(wsrc + off + (lane << 4), (char*)&wch[0][0] + off);
    }
  }
  asm volatile("s_waitcnt vmcnt(0)" ::: "memory");
  __syncthreads();

  f32x4 acc[4][4];
  #pragma unroll
  for (int i = 0; i < 4; ++i)
    #pragma unroll
    for (int j = 0; j < 4; ++j) acc[i][j] = (f32x4){0.f, 0.f, 0.f, 0.f};

  for (int c = 0; c < 14; ++c){
    int cur = c & 1;
    if (c < 13){
      const char* wsrc = (const char*)wcv + (size_t)(c + 1) * 16384;
      #pragma unroll
      for (int is = 0; is < 4; ++is){
        int off = is * 4096 + wv * 1024;
        GLDS16(wsrc + off + (lane << 4), (char*)&wch[cur ^ 1][0] + off);
      }
    }
    int k = c >> 1;
    const char* wb = (const char*)&wch[cur][0];
    #pragma unroll
    for (int ks = 0; ks < 2; ++ks){
      short8 af[4], bf[4];
      int j0 = ks * 32 + lhi * 8;
      #pragma unroll
      for (int mt = 0; mt < 4; ++mt){
        int co = wr * 64 + mt * 16 + lan15;
        af[mt] = *(const short8*)(wb + co * 128 + ((j0 * 2) ^ ((co & 7) << 4)));
      }
      int ci0 = (c & 1) * 64 + ks * 32 + lhi * 8;
      #pragma unroll
      for (int nt = 0; nt < 4; ++nt){
        int ll = wc * 64 + nt * 16 + lan15;
        int row = ll + k + 1;                  // staged row of source l = l0+ll+k-3
        int lg = l0 + ll + k - 3;
        bf[nt] = *(const short8*)((const char*)xt + row * 256 + ((ci0 * 2) ^ ((lg & 7) << 4)));
      }
      #pragma unroll
      for (int mt = 0; mt < 4; ++mt)
        #pragma unroll
        for (int nt = 0; nt < 4; ++nt)
          acc[mt][nt] = __builtin_amdgcn_mfma_f32_16x16x32_bf16(af[mt], bf[nt], acc[mt][nt], 0, 0, 0);
    }
    asm volatile("s_waitcnt vmcnt(0)" ::: "memory");
    __syncthreads();
  }

  // epilogue: bn (+res) relu -> fp32 out.  D: row(co)=(lane>>4)*4+reg, col(l)=lane&15
  bool hasres = (Xres != nullptr);
  #pragma unroll
  for (int mt = 0; mt < 4; ++mt){
    #pragma unroll
    for (int reg = 0; reg < 4; ++reg){
      int co = wr * 64 + mt * 16 + (lhi << 2) + reg;
      float A = bng[co] * 0.99999500003749968f;          // g / sqrt(1+1e-5)
      float Bc = fmaf(bnb[co], A, bnbe[co]);
      size_t rowb = ((size_t)b * HCH + co) * LSEQ;
      #pragma unroll
      for (int nt = 0; nt < 4; ++nt){
        int l = l0 + wc * 64 + nt * 16 + lan15;
        float v = fmaf(acc[mt][nt][reg], A, Bc);
        if (hasres) v += Xres[rowb + l];
        v = fmaxf(v, 0.f);
        Xout[rowb + l] = v;
      }
    }
  }
}

// ---------------- DSS recurrence: one wave per (b,h); lanes 0-31 fwd states, 32-63 bwd ----------------
// Yf[l] = D*x[l] + Re(sum_n u_n[l]),  u = r u + Wc0 x   (left-to-right)
// Yb[l] = Re(sum_n v_n[l]),           v = r v + Wc1 x[l+1] (right-to-left)
__global__ __launch_bounds__(64) void k_dss(const float* __restrict__ X, const float* __restrict__ pp,
                                            const float* __restrict__ Dv,
                                            float* __restrict__ Yf, float* __restrict__ Yb){
  int row = blockIdx.x;
  int h = row & (HCH - 1);
  int lane = threadIdx.x;
  int half = lane >> 5, n = lane & 31;
  float rre = pp[(0 * HCH + h) * NST + n];
  float rim = pp[(1 * HCH + h) * NST + n];
  float wre = pp[((2 + 2 * half) * HCH + h) * NST + n];
  float wim = pp[((3 + 2 * half) * HCH + h) * NST + n];
  float Dh = Dv[h];
  const float* xrow = X + (size_t)row * LSEQ;
  float* yout = half ? (Yb + (size_t)row * LSEQ) : (Yf + (size_t)row * LSEQ);
  __shared__ float xsh[2][32];
  __shared__ float cbuf[2][32][33];
  float ure = 0.f, uim = 0.f;
  int l0 = half ? (LSEQ - 32) : 0;
  float xv = xrow[l0 + n];
  float xl = 0.f;                                  // x just past the top of bwd chunk (x[L]=0)
  for (int c = 0; c < 256; ++c){
    xsh[half][half ? (31 - n) : n] = xv;           // bwd stored reversed -> affine step index
    __syncthreads();
    float x0 = half ? xl : xsh[0][0];
    int l0n = half ? (LSEQ - 64 - c * 32) : (c * 32 + 32);
    if (c < 255){                                  // prefetch next chunk (hidden under compute)
      xv = xrow[l0n + n];
      if (half) xl = xrow[l0n + 32];
    }
    const float* xb = &xsh[half][0] - half;        // step j reads xb[j] (j>=1)
    float* cb = &cbuf[half][0][n];
    #pragma unroll
    for (int j = 0; j < 32; ++j){
      float xj = (j == 0) ? x0 : xb[j];
      float tre = fmaf(rre, ure, wre * xj);
      tre = fmaf(-rim, uim, tre);
      float tim = fmaf(rre, uim, wim * xj);
      tim = fmaf(rim, ure, tim);
      ure = tre; uim = tim;
      cb[j * 33] = ure;                            // real part = output contribution
    }
    __syncthreads();
    int rr = half ? (31 - n) : n;                  // transpose-reduce over 32 states
    const float* crow = &cbuf[half][rr][0];
    float s = 0.f;
    #pragma unroll
    for (int i = 0; i < 32; ++i) s += crow[i];
    if (!half) s = fmaf(Dh, xsh[0][n], s);
    yout[l0 + n] = s;
    __syncthreads();
    l0 = l0n;
  }
}

// ---------------- fused: g1=gelu(Yf+Yb); y=out_w@g1+out_b; GLU; +X; channel-LN -> X ----------------
__global__ __launch_bounds__(256) void k_glu(
    const float* __restrict__ Yf, const float* __restrict__ Yb,
    const float* __restrict__ ow, const float* __restrict__ ob,
    const float* __restrict__ lng, const float* __restrict__ lnb,
    float* __restrict__ X)
{
  int b = blockIdx.y, l0 = blockIdx.x * 64;
  int t = threadIdx.x;
  __shared__ float g1[128][68];
  __shared__ float wch[256][17];
  #pragma unroll
  for (int it = 0; it < 32; ++it){
    int idx = t + it * 256;
    int ci = idx >> 6, j = idx & 63;
    size_t o = ((size_t)b * HCH + ci) * LSEQ + l0 + j;
    g1[ci][j] = geluf(Yf[o] + Yb[o]);
  }
  float acc[8][8];
  #pragma unroll
  for (int i = 0; i < 8; ++i)
    #pragma unroll
    for (int j = 0; j < 8; ++j) acc[i][j] = 0.f;
  int o0 = t & 31, lq = t >> 5;                    // o = o0 + 32*oi ; l = l0 + lq*8 + li
  for (int cc = 0; cc < 8; ++cc){
    __syncthreads();
    #pragma unroll
    for (int i = 0; i < 16; ++i){
      int e = t + 256 * i;
      int o = e >> 4, cj = e & 15;
      wch[o][cj] = ow[o * 128 + cc * 16 + cj];
    }
    __syncthreads();
    #pragma unroll
    for (int cj = 0; cj < 16; ++cj){
      int ci = cc * 16 + cj;
      float xv[8];
      #pragma unroll
      for (int li = 0; li < 8; ++li) xv[li] = g1[ci][lq * 8 + li];
      #pragma unroll
      for (int oi = 0; oi < 8; ++oi){
        float wv = wch[o0 + 32 * oi][cj];
        #pragma unroll
        for (int li = 0; li < 8; ++li) acc[oi][li] = fmaf(wv, xv[li], acc[oi][li]);
      }
    }
  }
  // GLU pairs (oi, oi+4) -> h = o0+32*oi ; add skip
  float u[4][8];
  #pragma unroll
  for (int hi = 0; hi < 4; ++hi){
    int hch = o0 + 32 * hi;
    float ba = ob[hch], bg = ob[hch + 128];
    size_t rowo = ((size_t)b * HCH + hch) * LSEQ + l0 + (size_t)lq * 8;
    f32x4 sk0 = *(const f32x4*)&X[rowo];
    f32x4 sk1 = *(const f32x4*)&X[rowo + 4];
    #pragma unroll
    for (int li = 0; li < 8; ++li){
      float a = acc[hi][li] + ba;
      float g = acc[hi + 4][li] + bg;
      float z = a * (1.f / (1.f + expf(-g)));
      u[hi][li] = z + ((li < 4) ? sk0[li] : sk1[li - 4]);
    }
  }
  // LayerNorm over 128 channels: 4 regs/thread x 32 lanes (same lq group)
  float s1[8], s2[8];
  #pragma unroll
  for (int li = 0; li < 8; ++li){
    s1[li] = u[0][li] + u[1][li] + u[2][li] + u[3][li];
    s2[li] = u[0][li] * u[0][li] + u[1][li] * u[1][li] + u[2][li] * u[2][li] + u[3][li] * u[3][li];
  }
  #pragma unroll
  for (int m = 1; m < 32; m <<= 1){
    #pragma unroll
    for (int li = 0; li < 8; ++li){
      s1[li] += __shfl_xor(s1[li], m, 64);
      s2[li] += __shfl_xor(s2[li], m, 64);
    }
  }
  float mu[8], rs[8];
  #pragma unroll
  for (int li = 0; li < 8; ++li){
    mu[li] = s1[li] * (1.f / 128.f);
    float var = s2[li] * (1.f / 128.f) - mu[li] * mu[li];
    rs[li] = rsqrtf(var + 1e-5f);
  }
  #pragma unroll
  for (int hi = 0; hi < 4; ++hi){
    int hch = o0 + 32 * hi;
    float gg = lng[hch], bb = lnb[hch];
    size_t rowo = ((size_t)b * HCH + hch) * LSEQ + l0 + (size_t)lq * 8;
    f32x4 w0, w1;
    #pragma unroll
    for (int li = 0; li < 4; ++li) w0[li] = (u[hi][li] - mu[li]) * rs[li] * gg + bb;
    #pragma unroll
    for (int li = 4; li < 8; ++li) w1[li - 4] = (u[hi][li] - mu[li]) * rs[li] * gg + bb;
    *(f32x4*)&X[rowo]     = w0;
    *(f32x4*)&X[rowo + 4] = w1;
  }
}

// ---------------- decoder conv: (B,128,L) -> (B,5,L), K=15 'same', fp32 ----------------
__global__ __launch_bounds__(64) void k_dec(const float* __restrict__ X, const float* __restrict__ w,
                                            const float* __restrict__ bias, float* __restrict__ out){
  int b = blockIdx.y, l0 = blockIdx.x * 64;
  int t = threadIdx.x;
  __shared__ float xs[128][78];
  __shared__ float ws[5 * 128 * 15];
  for (int i = t; i < 128 * 78; i += 64){
    int ci = i / 78, j = i % 78;
    int l = l0 - 7 + j;
    xs[ci][j] = (l >= 0 && l < LSEQ) ? X[((size_t)b * HCH + ci) * LSEQ + l] : 0.f;
  }
  for (int i = t; i < 5 * 128 * 15; i += 64) ws[i] = w[i];
  __syncthreads();
  float acc[5] = {0, 0, 0, 0, 0};
  for (int ci = 0; ci < 128; ++ci){
    float xv[15];
    #pragma unroll
    for (int k = 0; k < 15; ++k) xv[k] = xs[ci][t + k];
    #pragma unroll
    for (int o = 0; o < 5; ++o){
      #pragma unroll
      for (int k = 0; k < 15; ++k)
        acc[o] = fmaf(ws[(o * 128 + ci) * 15 + k], xv[k], acc[o]);
    }
  }
  #pragma unroll
  for (int o = 0; o < 5; ++o)
    out[((size_t)b * 5 + o) * LSEQ + l0 + t] = acc[o] + bias[o];
}

extern "C" void kernel_launch(void* const* d_in, const int* in_sizes, int n_in,
                              void* d_out, int out_size, void* d_ws, size_t ws_size,
                              hipStream_t stream){
  (void)in_sizes; (void)n_in; (void)out_size; (void)ws_size;
  const float* x_in   = (const float*)d_in[0];
  const float* enc_w  = (const float*)d_in[1];
  const float* enc_b  = (const float*)d_in[2];
  const float* rn_w1  = (const float*)d_in[3];
  const float* rn_b1  = (const float*)d_in[4];
  const float* rn_g1  = (const float*)d_in[5];
  const float* rn_be1 = (const float*)d_in[6];
  const float* rn_w2  = (const float*)d_in[7];
  const float* rn_b2  = (const float*)d_in[8];
  const float* rn_g2  = (const float*)d_in[9];
  const float* rn_be2 = (const float*)d_in[10];
  const float* lam_re = (const float*)d_in[11];
  const float* lam_im = (const float*)d_in[12];
  const float* log_dt = (const float*)d_in[13];
  const float* W_re   = (const float*)d_in[14];
  const float* W_im   = (const float*)d_in[15];
  const float* Dv     = (const float*)d_in[16];
  const float* out_w  = (const float*)d_in[17];
  const float* out_b  = (const float*)d_in[18];
  const float* ln_g   = (const float*)d_in[19];
  const float* ln_b   = (const float*)d_in[20];
  const float* dec_w  = (const float*)d_in[21];
  const float* dec_b  = (const float*)d_in[22];

  char* ws = (char*)d_ws;
  float* X    = (float*)(ws + 0ull);            // 64 MB
  float* Yf   = (float*)(ws + 67108864ull);     // 64 MB (also conv1 temp)
  float* Yb   = (float*)(ws + 134217728ull);    // 64 MB
  u16*   xTs  = (u16*)  (ws + 201326592ull);    // 33.6 MB bf16 transposed+swizzled
  u16*   wswz = (u16*)  (ws + 234946560ull);    // 1.35 MB
  float* dssp = (float*)(ws + 236322816ull);    // 384 KB

  k_xpad<<<16, 256, 0, stream>>>(xTs);
  k_wxform<<<2688, 256, 0, stream>>>(rn_w1, rn_w2, wswz);
  k_dssprep<<<64, 256, 0, stream>>>(lam_re, lam_im, log_dt, W_re, W_im, dssp);
  k_enc<<<dim3(128, 16), 128, 0, stream>>>(x_in, enc_w, enc_b, X);

  for (int r = 0; r < 3; ++r){
    k_xform<<<dim3(128, 16), 256, 0, stream>>>(X, xTs);
    k_conv<<<dim3(64, 16), 256, 0, stream>>>(xTs, (const u16*)((char*)wswz + (size_t)(2 * r) * 229376),
        rn_g1 + r * HCH, rn_b1 + r * HCH, rn_be1 + r * HCH, nullptr, Yf);
    k_xform<<<dim3(128, 16), 256, 0, stream>>>(Yf, xTs);
    k_conv<<<dim3(64, 16), 256, 0, stream>>>(xTs, (const u16*)((char*)wswz + (size_t)(2 * r + 1) * 229376),
        rn_g2 + r * HCH, rn_b2 + r * HCH, rn_be2 + r * HCH, X, X);
  }
  for (int dl = 0; dl < NLAY; ++dl){
    k_dss<<<2048, 64, 0, stream>>>(X, dssp + (size_t)dl * 6 * HCH * NST, Dv + dl * HCH, Yf, Yb);
    k_glu<<<dim3(128, 16), 256, 0, stream>>>(Yf, Yb, out_w + (size_t)dl * 256 * HCH, out_b + dl * 256,
        ln_g + dl * HCH, ln_b + dl * HCH, X);
  }
  k_dec<<<dim3(128, 16), 64, 0, stream>>>(X, dec_w, dec_b, (float*)d_out);
}

// Round 3
// 2190.418 us; speedup vs baseline: 1.5447x; 1.5447x over previous
//
#include <hip/hip_runtime.h>
#include <hip/hip_bf16.h>

// DSSResNet on MI355X.
//  enc(fp32) -> 3x { conv(MFMA bf16) x2 } -> 4x { chunked-SSM DSS (compensated bf16 MFMA) -> GLU+LN } -> dec(MFMA)
// DSS chunking (C=128): y[i] = T@x (intra) + Re(r^{i+1} Sf) + Re(r^{127-i} Sb); S via 64-step chunk scan.
// Precision: A*x = Ah*xh + Ah*xl + Al*xh (hi/lo bf16 compensation); P fp32; S hi/lo bf16.

#define BN   16
#define HCH  128
#define LSEQ 8192
#define NST  32
#define NLAY 4
#define XT_BSTRIDE 2101248ull   // 8208 rows (l=-8..8199) * 256 B per b

typedef __attribute__((ext_vector_type(4))) float f32x4;
typedef __attribute__((ext_vector_type(8))) short short8;
typedef unsigned short u16;
typedef unsigned int   u32;

struct __align__(8) U2 { u32 x, y; };
struct __align__(16) US8 { u16 v[8]; };

__device__ __forceinline__ u16 f2bf(float f){
  union { float f; u32 u; } v; v.f = f;
  u32 u = v.u;
  return (u16)((u + 0x7fffu + ((u >> 16) & 1u)) >> 16);   // RNE
}
__device__ __forceinline__ float bf2f(u32 lo16){
  union { u32 u; float f; } v; v.u = lo16 << 16; return v.f;
}
__device__ __forceinline__ float geluf(float v){
  return 0.5f * v * (1.0f + erff(v * 0.70710678118654752f));
}

#define GLDS16(g, l) \
  __builtin_amdgcn_global_load_lds((const __attribute__((address_space(1))) u32*)(g), \
                                   (__attribute__((address_space(3))) u32*)(l), 16, 0, 0)

// ---------------- zero xTs halo rows (l=-8..-1, 8192..8199) ----------------
__global__ void k_xpad(u16* xTs){
  int b = blockIdx.x, t = threadIdx.x;
  char* base = (char*)xTs + (size_t)b * XT_BSTRIDE;
  int r = t >> 4;
  int row = (r < 8) ? r : (8192 + r);          // rows 0..7 and 8200..8207
  f32x4 z = {0.f, 0.f, 0.f, 0.f};
  *(f32x4*)(base + (size_t)row * 256 + (size_t)(t & 15) * 16) = z;
}

// ---------------- resnet weights -> bf16, K-major (k*128+ci), chunked+swizzled ----------------
__global__ void k_wxform(const float* __restrict__ w1, const float* __restrict__ w2, u16* __restrict__ wswz){
  int idx = blockIdx.x * 256 + threadIdx.x;
  if (idx >= 6 * 128 * 896) return;
  int conv = idx / (128 * 896);
  int rem  = idx % (128 * 896);
  int co = rem / 896, K = rem % 896;
  int k = K >> 7, ci = K & 127;
  const float* src = (conv & 1) ? w2 : w1;
  int blk = conv >> 1;
  float v = src[(((size_t)blk * 128 + co) * 128 + ci) * 7 + k];
  int chunk = K >> 6, j = K & 63;
  size_t byteoff = (size_t)conv * 229376 + (size_t)chunk * 16384 + (size_t)co * 128
                 + (u32)((j * 2) ^ ((co & 7) << 4));
  *(u16*)((char*)wswz + byteoff) = f2bf(v);
}

// ---------------- decoder weights -> bf16 [16co][1920K] swizzled ----------------
__global__ void k_wdec(const float* __restrict__ dw, u16* __restrict__ wd){
  int idx = blockIdx.x * 256 + threadIdx.x;
  if (idx >= 16 * 1920) return;
  int co = idx / 1920, K = idx % 1920;
  int k = K >> 7, ci = K & 127;
  float v = (co < 5) ? dw[((size_t)co * 128 + ci) * 15 + k] : 0.f;
  size_t byteoff = (size_t)co * 3840 + (u32)((K * 2) ^ ((co & 7) << 4));
  *(u16*)((char*)wd + byteoff) = f2bf(v);
}

// ---------------- DSS per-layer params: r = exp(dt*Lam), Wc = W*(r-1)/Lam ----------------
// dssp layout per layer: [6][H][N] : 0 r_re, 1 r_im, 2 wc0_re, 3 wc0_im, 4 wc1_re, 5 wc1_im
__global__ void k_dssprep(const float* __restrict__ lam_re, const float* __restrict__ lam_im,
                          const float* __restrict__ log_dt, const float* __restrict__ W_re,
                          const float* __restrict__ W_im, float* __restrict__ dssp){
  int idx = blockIdx.x * 256 + threadIdx.x;
  if (idx >= NLAY * HCH * NST) return;
  int layer = idx / (HCH * NST);
  int hn = idx % (HCH * NST);
  int h = hn / NST, n = hn % NST;
  float Lre = -expf(lam_re[layer * NST + n]);
  float Lim = lam_im[layer * NST + n];
  float dt  = expf(log_dt[layer * HCH + h]);
  float are = dt * Lre, aim = dt * Lim;
  float er = expf(are);
  float rre = er * cosf(aim);
  float rim = er * sinf(aim);
  float nre = rre - 1.f, nim = rim;
  float den = 1.f / (Lre * Lre + Lim * Lim);
  float fre = (nre * Lre + nim * Lim) * den;
  float fim = (nim * Lre - nre * Lim) * den;
  float* base = dssp + (size_t)layer * 6 * HCH * NST;
  base[(0 * HCH + h) * NST + n] = rre;
  base[(1 * HCH + h) * NST + n] = rim;
  #pragma unroll
  for (int cc = 0; cc < 2; ++cc){
    float wr_ = W_re[(((size_t)layer * 2 + cc) * HCH + h) * NST + n];
    float wi_ = W_im[(((size_t)layer * 2 + cc) * HCH + h) * NST + n];
    base[((2 + 2 * cc) * HCH + h) * NST + n] = wr_ * fre - wi_ * fim;
    base[((3 + 2 * cc) * HCH + h) * NST + n] = wr_ * fim + wi_ * fre;
  }
}

// ---------------- per-layer chunk matrices (hi/lo bf16, swizzled slices) ----------------
// A1c per h: 4 slices [128 q][64 k]: a0=A1h(k 0:64), a1=A1h(64:128), a2=A1l(0:64), a3=A1l(64:128)
//   A1[q][j]: q<64 fwd (n=q>>1, im=q&1, coeff w0*r^(127-j)); q>=64 bwd (w1*r^j)
// A2c per h: 8 slices [128 i][64 k]: a0,a1=Th halves; a2,a3=Tl halves; a4=Vfh a5=Vfl a6=Vbh a7=Vbl
//   T[i][c] = (i>=c) ? tf[i-c] : tb[c-i];  tf[d]=Re(sum w0 r^d), tb[d]=Re(sum w1 r^(d-1))
//   Vf[i][k]: p=i+1; Vb: p=127-i; value (k even)=Re(r^p), (k odd)=-Im(r^p)
__global__ __launch_bounds__(256) void k_mats(const float* __restrict__ pp,
                                              u16* __restrict__ A1c, u16* __restrict__ A2c,
                                              float* __restrict__ rC){
  int h = blockIdx.x, t = threadIdx.x;
  __shared__ float pre[129][33], pim[129][33];
  __shared__ float w0re[32], w0im[32], w1re[32], w1im[32];
  __shared__ float tf[128], tb[128];
  if (t < 32){
    int n = t;
    float rre = pp[(0 * HCH + h) * NST + n], rim = pp[(1 * HCH + h) * NST + n];
    w0re[n] = pp[(2 * HCH + h) * NST + n]; w0im[n] = pp[(3 * HCH + h) * NST + n];
    w1re[n] = pp[(4 * HCH + h) * NST + n]; w1im[n] = pp[(5 * HCH + h) * NST + n];
    float pr = 1.f, pi = 0.f;
    pre[0][n] = 1.f; pim[0][n] = 0.f;
    for (int p = 1; p <= 128; ++p){
      float nr = pr * rre - pi * rim;
      float ni = pr * rim + pi * rre;
      pr = nr; pi = ni;
      pre[p][n] = pr; pim[p][n] = pi;
    }
    rC[h * 64 + 2 * n] = pr; rC[h * 64 + 2 * n + 1] = pi;
  }
  __syncthreads();
  if (t < 128){
    float s = 0.f;
    for (int n = 0; n < 32; ++n) s += w0re[n] * pre[t][n] - w0im[n] * pim[t][n];
    tf[t] = s;
  } else {
    int d = t - 128;
    if (d == 0) tb[0] = 0.f;
    else {
      float s = 0.f;
      for (int n = 0; n < 32; ++n) s += w1re[n] * pre[d - 1][n] - w1im[n] * pim[d - 1][n];
      tb[d] = s;
    }
  }
  __syncthreads();
  for (int idx = t; idx < 4 * 128 * 64; idx += 256){
    int a = idx >> 13, rem = idx & 8191, q = rem >> 6, k = rem & 63;
    int j = (a & 1) * 64 + k;
    int n, p; float wr_, wi_;
    if (q < 64){ n = q >> 1; p = 127 - j; wr_ = w0re[n]; wi_ = w0im[n]; }
    else       { n = (q - 64) >> 1; p = j; wr_ = w1re[n]; wi_ = w1im[n]; }
    float pr = pre[p][n], pi = pim[p][n];
    float v = (q & 1) ? (wr_ * pi + wi_ * pr) : (wr_ * pr - wi_ * pi);
    u16 hb = f2bf(v);
    u16 ob = (a < 2) ? hb : f2bf(v - bf2f(hb));
    *(u16*)((char*)A1c + (size_t)h * 65536 + (size_t)a * 16384 + (size_t)q * 128
            + (u32)((k * 2) ^ ((q & 7) << 4))) = ob;
  }
  for (int idx = t; idx < 8 * 128 * 64; idx += 256){
    int a = idx >> 13, rem = idx & 8191, i = rem >> 6, k = rem & 63;
    float v; bool lo;
    if (a < 4){
      int colT = (a & 1) * 64 + k;
      v = (i >= colT) ? tf[i - colT] : tb[colT - i];
      lo = (a >= 2);
    } else {
      int n = k >> 1;
      int p = (a < 6) ? (i + 1) : (127 - i);
      v = (k & 1) ? -pim[p][n] : pre[p][n];
      lo = (a == 5) || (a == 7);
    }
    u16 hb = f2bf(v);
    u16 ob = lo ? f2bf(v - bf2f(hb)) : hb;
    *(u16*)((char*)A2c + (size_t)h * 131072 + (size_t)a * 16384 + (size_t)i * 128
            + (u32)((k * 2) ^ ((i & 7) << 4))) = ob;
  }
}

// ---------------- encoder conv: (B,5,L) -> (B,128,L), K=15 'same', fp32 ----------------
__global__ __launch_bounds__(128) void k_enc(const float* __restrict__ xin, const float* __restrict__ w,
                                             const float* __restrict__ bias, float* __restrict__ X){
  int b = blockIdx.y, l0 = blockIdx.x * 64;
  int t = threadIdx.x;                       // t = co
  __shared__ float xs[5][78];
  for (int i = t; i < 5 * 78; i += 128){
    int ci = i / 78, j = i % 78;
    int l = l0 - 7 + j;
    xs[ci][j] = (l >= 0 && l < LSEQ) ? xin[((size_t)b * 5 + ci) * LSEQ + l] : 0.f;
  }
  float wreg[75];
  #pragma unroll
  for (int i = 0; i < 75; ++i) wreg[i] = w[t * 75 + i];
  float bc = bias[t];
  __syncthreads();
  size_t orow = ((size_t)b * HCH + t) * LSEQ + l0;
  for (int gb = 0; gb < 8; ++gb){
    float acc[8] = {0, 0, 0, 0, 0, 0, 0, 0};
    #pragma unroll
    for (int ci = 0; ci < 5; ++ci){
      #pragma unroll
      for (int k = 0; k < 15; ++k){
        float wv = wreg[ci * 15 + k];
        #pragma unroll
        for (int j = 0; j < 8; ++j)
          acc[j] = fmaf(wv, xs[ci][gb * 8 + j + k], acc[j]);
      }
    }
    f32x4 o0 = {acc[0] + bc, acc[1] + bc, acc[2] + bc, acc[3] + bc};
    f32x4 o1 = {acc[4] + bc, acc[5] + bc, acc[6] + bc, acc[7] + bc};
    *(f32x4*)&X[orow + gb * 8]     = o0;
    *(f32x4*)&X[orow + gb * 8 + 4] = o1;
  }
}

// ---------------- X (b,h,l) fp32 -> xTs (b,l,ci) bf16, row-swizzled by (l&7) ----------------
__global__ __launch_bounds__(256) void k_xform(const float* __restrict__ Xin, u16* __restrict__ xTs){
  int b = blockIdx.y, l0 = blockIdx.x * 64;
  int t = threadIdx.x;
  __shared__ float tile[128][65];
  #pragma unroll
  for (int it = 0; it < 32; ++it){
    int idx = t + it * 256;
    int ci = idx >> 6, j = idx & 63;
    tile[ci][j] = Xin[((size_t)b * HCH + ci) * LSEQ + l0 + j];
  }
  __syncthreads();
  int rl = t >> 2, q = t & 3;
  int l = l0 + rl;
  char* rowp = (char*)xTs + (size_t)b * XT_BSTRIDE + (size_t)(l + 8) * 256;
  u32 key = ((u32)l & 7u) << 4;
  #pragma unroll
  for (int ii = 0; ii < 8; ++ii){
    int c0 = q * 32 + ii * 4;
    U2 val;
    val.x = (u32)f2bf(tile[c0 + 0][rl]) | ((u32)f2bf(tile[c0 + 1][rl]) << 16);
    val.y = (u32)f2bf(tile[c0 + 2][rl]) | ((u32)f2bf(tile[c0 + 3][rl]) << 16);
    *(U2*)(rowp + (((u32)(c0 * 2)) ^ key)) = val;
  }
}

// ---------------- resnet conv (K=7) as MFMA GEMM ----------------
__global__ __launch_bounds__(256, 2) void k_conv(
    const u16* __restrict__ xTs, const u16* __restrict__ wcv,
    const float* __restrict__ bng, const float* __restrict__ bnb, const float* __restrict__ bnbe,
    const float* __restrict__ Xres, float* __restrict__ Xout)
{
  int b = blockIdx.y, l0 = blockIdx.x * 128;
  int tid = threadIdx.x, lane = tid & 63, wv = tid >> 6;
  int wr = wv >> 1, wc = wv & 1;
  int lan15 = lane & 15, lhi = lane >> 4;

  __shared__ alignas(16) u16 xt[144 * 128];
  __shared__ alignas(16) u16 wch[2][128 * 64];

  const char* xsrc = (const char*)xTs + (size_t)b * XT_BSTRIDE + (size_t)l0 * 256;
  #pragma unroll
  for (int is = 0; is < 9; ++is){
    int off = is * 4096 + wv * 1024;
    GLDS16(xsrc + off + (lane << 4), (char*)xt + off);
  }
  {
    const char* wsrc = (const char*)wcv;
    #pragma unroll
    for (int is = 0; is < 4; ++is){
      int off = is * 4096 + wv * 1024;
      GLDS16(wsrc + off + (lane << 4), (char*)&wch[0][0] + off);
    }
  }
  asm volatile("s_waitcnt vmcnt(0)" ::: "memory");
  __syncthreads();

  f32x4 acc[4][4];
  #pragma unroll
  for (int i = 0; i < 4; ++i)
    #pragma unroll
    for (int j = 0; j < 4; ++j) acc[i][j] = (f32x4){0.f, 0.f, 0.f, 0.f};

  for (int c = 0; c < 14; ++c){
    int cur = c & 1;
    if (c < 13){
      const char* wsrc = (const char*)wcv + (size_t)(c + 1) * 16384;
      #pragma unroll
      for (int is = 0; is < 4; ++is){
        int off = is * 4096 + wv * 1024;
        GLDS16(wsrc + off + (lane << 4), (char*)&wch[cur ^ 1][0] + off);
      }
    }
    int k = c >> 1;
    const char* wb = (const char*)&wch[cur][0];
    #pragma unroll
    for (int ks = 0; ks < 2; ++ks){
      short8 af[4], bf[4];
      int j0 = ks * 32 + lhi * 8;
      #pragma unroll
      for (int mt = 0; mt < 4; ++mt){
        int co = wr * 64 + mt * 16 + lan15;
        af[mt] = *(const short8*)(wb + co * 128 + ((j0 * 2) ^ ((co & 7) << 4)));
      }
      int ci0 = (c & 1) * 64 + ks * 32 + lhi * 8;
      #pragma unroll
      for (int nt = 0; nt < 4; ++nt){
        int ll = wc * 64 + nt * 16 + lan15;
        int row = ll + k + 5;                  // staged row of source l = l0+ll+k-3 (halo 8)
        int lg = l0 + ll + k - 3;
        bf[nt] = *(const short8*)((const char*)xt + row * 256 + ((ci0 * 2) ^ ((lg & 7) << 4)));
      }
      #pragma unroll
      for (int mt = 0; mt < 4; ++mt)
        #pragma unroll
        for (int nt = 0; nt < 4; ++nt)
          acc[mt][nt] = __builtin_amdgcn_mfma_f32_16x16x32_bf16(af[mt], bf[nt], acc[mt][nt], 0, 0, 0);
    }
    asm volatile("s_waitcnt vmcnt(0)" ::: "memory");
    __syncthreads();
  }

  bool hasres = (Xres != nullptr);
  #pragma unroll
  for (int mt = 0; mt < 4; ++mt){
    #pragma unroll
    for (int reg = 0; reg < 4; ++reg){
      int co = wr * 64 + mt * 16 + (lhi << 2) + reg;
      float A = bng[co] * 0.99999500003749968f;
      float Bc = fmaf(bnb[co], A, bnbe[co]);
      size_t rowb = ((size_t)b * HCH + co) * LSEQ;
      #pragma unroll
      for (int nt = 0; nt < 4; ++nt){
        int l = l0 + wc * 64 + nt * 16 + lan15;
        float v = fmaf(acc[mt][nt][reg], A, Bc);
        if (hasres) v += Xres[rowb + l];
        v = fmaxf(v, 0.f);
        Xout[rowb + l] = v;
      }
    }
  }
}

// ---------------- stage x tile (hi/lo bf16) into LDS: [128 col][128 k], col=(c&7)*16+b ----------------
__device__ __forceinline__ void stage_x_tile(const float* __restrict__ X, int h, int ct,
                                             char* xh, char* xl, int t){
  int k8 = t & 15;            // k-group: k = k8*8
  int c0 = t >> 4;            // base col
  #pragma unroll
  for (int it = 0; it < 8; ++it){
    int col = c0 + it * 16;
    int c = ct * 8 + (col >> 4), b = col & 15;
    const float* src = X + ((size_t)b * HCH + h) * LSEQ + (size_t)c * 128 + k8 * 8;
    f32x4 v0 = *(const f32x4*)src;
    f32x4 v1 = *(const f32x4*)(src + 4);
    US8 hi, lo;
    #pragma unroll
    for (int e = 0; e < 4; ++e){
      u16 hb = f2bf(v0[e]);
      hi.v[e] = hb; lo.v[e] = f2bf(v0[e] - bf2f(hb));
      u16 hb2 = f2bf(v1[e]);
      hi.v[e + 4] = hb2; lo.v[e + 4] = f2bf(v1[e] - bf2f(hb2));
    }
    u32 off = (u32)col * 256 + (u32)((k8 * 16) ^ ((col & 7) << 4));
    *(US8*)(xh + off) = hi;
    *(US8*)(xl + off) = lo;
  }
}

// ---------------- GEMM1: P[128q][col] = A1h@xh + A1h@xl + A1l@xh (per h,ct) ----------------
__global__ __launch_bounds__(256) void k_dss1(const float* __restrict__ X,
                                              const u16* __restrict__ A1c,
                                              float* __restrict__ P){
  int ct = blockIdx.x, h = blockIdx.y;
  int tid = threadIdx.x, lane = tid & 63, wv = tid >> 6;
  int wr = wv >> 1, wc = wv & 1, lan15 = lane & 15, lhi = lane >> 4;
  __shared__ alignas(16) u16 bx[32768];      // xh [0,32KB) xl [32KB,64KB)
  __shared__ alignas(16) u16 ach[2][8192];

  stage_x_tile(X, h, ct, (char*)bx, (char*)bx + 32768, tid);
  const char* abase = (const char*)A1c + (size_t)h * 65536;
  #pragma unroll
  for (int is = 0; is < 4; ++is){
    int off = is * 4096 + wv * 1024;
    GLDS16(abase + off + (lane << 4), (char*)&ach[0][0] + off);
  }
  asm volatile("s_waitcnt vmcnt(0)" ::: "memory");
  __syncthreads();

  f32x4 acc[4][4];
  #pragma unroll
  for (int i = 0; i < 4; ++i)
    #pragma unroll
    for (int j = 0; j < 4; ++j) acc[i][j] = (f32x4){0.f, 0.f, 0.f, 0.f};

  const int asel[6] = {0, 1, 0, 1, 2, 3};
  const int bsel[6] = {0, 0, 1, 1, 0, 0};
  const int bk0 [6] = {0, 64, 0, 64, 0, 64};
  #pragma unroll
  for (int s = 0; s < 6; ++s){
    if (s < 5){
      const char* an = abase + (size_t)asel[s + 1] * 16384;
      #pragma unroll
      for (int is = 0; is < 4; ++is){
        int off = is * 4096 + wv * 1024;
        GLDS16(an + off + (lane << 4), (char*)&ach[(s + 1) & 1][0] + off);
      }
    }
    const char* bt = (const char*)bx + bsel[s] * 32768;
    const char* at = (const char*)&ach[s & 1][0];
    #pragma unroll
    for (int ks = 0; ks < 2; ++ks){
      int ka = ks * 32 + lhi * 8;
      short8 af[4], bf[4];
      #pragma unroll
      for (int mt = 0; mt < 4; ++mt){
        int q = wr * 64 + mt * 16 + lan15;
        af[mt] = *(const short8*)(at + q * 128 + ((ka * 2) ^ ((q & 7) << 4)));
      }
      int kb = bk0[s] + ka;
      #pragma unroll
      for (int nt = 0; nt < 4; ++nt){
        int col = wc * 64 + nt * 16 + lan15;
        bf[nt] = *(const short8*)(bt + col * 256 + ((kb * 2) ^ ((col & 7) << 4)));
      }
      #pragma unroll
      for (int mt = 0; mt < 4; ++mt)
        #pragma unroll
        for (int nt = 0; nt < 4; ++nt)
          acc[mt][nt] = __builtin_amdgcn_mfma_f32_16x16x32_bf16(af[mt], bf[nt], acc[mt][nt], 0, 0, 0);
    }
    asm volatile("s_waitcnt vmcnt(0)" ::: "memory");
    __syncthreads();
  }

  #pragma unroll
  for (int mt = 0; mt < 4; ++mt)
    #pragma unroll
    for (int nt = 0; nt < 4; ++nt){
      int col = ct * 128 + wc * 64 + nt * 16 + lan15;
      int q0 = wr * 64 + mt * 16 + (lhi << 2);
      *(f32x4*)&P[((size_t)h * 1024 + col) * 128 + q0] = acc[mt][nt];
    }
}

// ---------------- chunk scan (fp32): S[c] written (hi/lo bf16, swizzled) before update ----------------
__global__ __launch_bounds__(256) void k_scan(const float* __restrict__ P,
                                              const float* __restrict__ rC,
                                              u16* __restrict__ Sf, u16* __restrict__ Sb){
  int part = blockIdx.x & 3, h = blockIdx.x >> 2;
  int t = threadIdx.x;
  int dir = part >> 1;
  int b = (part & 1) * 8 + (t >> 5);
  int n = t & 31;
  float rre = rC[h * 64 + 2 * n], rim = rC[h * 64 + 2 * n + 1];
  u16* SO = dir ? Sb : Sf;
  const float* pbase = P + (size_t)h * 131072 + (size_t)b * 128 + dir * 64 + 2 * n;
  float sre = 0.f, sim = 0.f;
  u32 key = ((u32)b & 7u) << 4;
  for (int ii = 0; ii < 64; ++ii){
    int c = dir ? (63 - ii) : ii;
    u16 hr = f2bf(sre), hm = f2bf(sim);
    u32 hw = (u32)hr | ((u32)hm << 16);
    u32 lw = (u32)f2bf(sre - bf2f(hr)) | ((u32)f2bf(sim - bf2f(hm)) << 16);
    char* sp = (char*)SO + ((size_t)(h * 8 + (c >> 3)) * 2) * 16384
             + (size_t)((c & 7) * 16 + b) * 128 + (u32)((4 * n) ^ key);
    *(u32*)sp = hw;
    *(u32*)(sp + 16384) = lw;
    const float* pp = pbase + (size_t)c * 2048;
    float pr = pp[0], pi = pp[1];
    float nr = rre * sre - rim * sim + pr;
    float ni = rre * sim + rim * sre + pi;
    sre = nr; sim = ni;
  }
}

// ---------------- GEMM2: Y = T@x + Vf@Sf + Vb@Sb (compensated); G = gelu(Y + D*x) ----------------
__global__ __launch_bounds__(256) void k_dss2(const float* __restrict__ X,
                                              const u16* __restrict__ A2c,
                                              const u16* __restrict__ Sf,
                                              const u16* __restrict__ Sb,
                                              const float* __restrict__ Dv,
                                              float* __restrict__ G){
  int ct = blockIdx.x, h = blockIdx.y;
  int tid = threadIdx.x, lane = tid & 63, wv = tid >> 6;
  int wr = wv >> 1, wc = wv & 1, lan15 = lane & 15, lhi = lane >> 4;
  __shared__ alignas(16) u16 bx[32768];      // phase T: xh|xl ; phase V: Sfh|Sfl|Sbh|Sbl (4x16KB)
  __shared__ alignas(16) u16 ach[2][8192];

  stage_x_tile(X, h, ct, (char*)bx, (char*)bx + 32768, tid);
  const char* abase = (const char*)A2c + (size_t)h * 131072;
  #pragma unroll
  for (int is = 0; is < 4; ++is){
    int off = is * 4096 + wv * 1024;
    GLDS16(abase + off + (lane << 4), (char*)&ach[0][0] + off);
  }
  asm volatile("s_waitcnt vmcnt(0)" ::: "memory");
  __syncthreads();

  f32x4 acc[4][4];
  #pragma unroll
  for (int i = 0; i < 4; ++i)
    #pragma unroll
    for (int j = 0; j < 4; ++j) acc[i][j] = (f32x4){0.f, 0.f, 0.f, 0.f};

  // ---- phase T: [Th|Th|Tl] x [xh;xl;xh] ----
  {
    const int asel[6] = {0, 1, 0, 1, 2, 3};
    const int bsel[6] = {0, 0, 1, 1, 0, 0};
    const int bk0 [6] = {0, 64, 0, 64, 0, 64};
    #pragma unroll
    for (int s = 0; s < 6; ++s){
      if (s < 5){
        const char* an = abase + (size_t)asel[s + 1] * 16384;
        #pragma unroll
        for (int is = 0; is < 4; ++is){
          int off = is * 4096 + wv * 1024;
          GLDS16(an + off + (lane << 4), (char*)&ach[(s + 1) & 1][0] + off);
        }
      }
      const char* bt = (const char*)bx + bsel[s] * 32768;
      const char* at = (const char*)&ach[s & 1][0];
      #pragma unroll
      for (int ks = 0; ks < 2; ++ks){
        int ka = ks * 32 + lhi * 8;
        short8 af[4], bf[4];
        #pragma unroll
        for (int mt = 0; mt < 4; ++mt){
          int i = wr * 64 + mt * 16 + lan15;
          af[mt] = *(const short8*)(at + i * 128 + ((ka * 2) ^ ((i & 7) << 4)));
        }
        int kb = bk0[s] + ka;
        #pragma unroll
        for (int nt = 0; nt < 4; ++nt){
          int col = wc * 64 + nt * 16 + lan15;
          bf[nt] = *(const short8*)(bt + col * 256 + ((kb * 2) ^ ((col & 7) << 4)));
        }
        #pragma unroll
        for (int mt = 0; mt < 4; ++mt)
          #pragma unroll
          for (int nt = 0; nt < 4; ++nt)
            acc[mt][nt] = __builtin_amdgcn_mfma_f32_16x16x32_bf16(af[mt], bf[nt], acc[mt][nt], 0, 0, 0);
      }
      asm volatile("s_waitcnt vmcnt(0)" ::: "memory");
      __syncthreads();
    }
  }
  // ---- boundary: restage B with S tiles + A slice 4 ----
  {
    const char* st0 = (const char*)Sf + ((size_t)(h * 8 + ct) * 2) * 16384;
    const char* st2 = (const char*)Sb + ((size_t)(h * 8 + ct) * 2) * 16384;
    const char* stile[4] = {st0, st0 + 16384, st2, st2 + 16384};
    #pragma unroll
    for (int tt = 0; tt < 4; ++tt){
      #pragma unroll
      for (int is = 0; is < 4; ++is){
        int off = is * 4096 + wv * 1024;
        GLDS16(stile[tt] + off + (lane << 4), (char*)bx + tt * 16384 + off);
      }
    }
    const char* an = abase + 4 * 16384;
    #pragma unroll
    for (int is = 0; is < 4; ++is){
      int off = is * 4096 + wv * 1024;
      GLDS16(an + off + (lane << 4), (char*)&ach[0][0] + off);
    }
    asm volatile("s_waitcnt vmcnt(0)" ::: "memory");
    __syncthreads();
  }
  // ---- phase V: Vfh*Sfh + Vfh*Sfl + Vfl*Sfh + Vbh*Sbh + Vbh*Sbl + Vbl*Sbh ----
  {
    const int asel[6] = {4, 4, 5, 6, 6, 7};
    const int bof [6] = {0, 16384, 0, 32768, 49152, 32768};
    #pragma unroll
    for (int s = 0; s < 6; ++s){
      if (s < 5){
        const char* an = abase + (size_t)asel[s + 1] * 16384;
        #pragma unroll
        for (int is = 0; is < 4; ++is){
          int off = is * 4096 + wv * 1024;
          GLDS16(an + off + (lane << 4), (char*)&ach[(s + 1) & 1][0] + off);
        }
      }
      const char* bt = (const char*)bx + bof[s];
      const char* at = (const char*)&ach[s & 1][0];
      #pragma unroll
      for (int ks = 0; ks < 2; ++ks){
        int ka = ks * 32 + lhi * 8;
        short8 af[4], bf[4];
        #pragma unroll
        for (int mt = 0; mt < 4; ++mt){
          int i = wr * 64 + mt * 16 + lan15;
          af[mt] = *(const short8*)(at + i * 128 + ((ka * 2) ^ ((i & 7) << 4)));
        }
        #pragma unroll
        for (int nt = 0; nt < 4; ++nt){
          int col = wc * 64 + nt * 16 + lan15;
          bf[nt] = *(const short8*)(bt + col * 128 + ((ka * 2) ^ ((col & 7) << 4)));
        }
        #pragma unroll
        for (int mt = 0; mt < 4; ++mt)
          #pragma unroll
          for (int nt = 0; nt < 4; ++nt)
            acc[mt][nt] = __builtin_amdgcn_mfma_f32_16x16x32_bf16(af[mt], bf[nt], acc[mt][nt], 0, 0, 0);
      }
      asm volatile("s_waitcnt vmcnt(0)" ::: "memory");
      __syncthreads();
    }
  }
  // ---- epilogue: G = gelu(Y + D*x), fp32 ----
  float Dh = Dv[h];
  #pragma unroll
  for (int mt = 0; mt < 4; ++mt)
    #pragma unroll
    for (int nt = 0; nt < 4; ++nt){
      int col = wc * 64 + nt * 16 + lan15;
      int c = ct * 8 + (col >> 4), b = col & 15;
      int i0 = wr * 64 + mt * 16 + (lhi << 2);
      size_t base = ((size_t)b * HCH + h) * LSEQ + (size_t)c * 128 + i0;
      f32x4 xv = *(const f32x4*)&X[base];
      f32x4 ov;
      #pragma unroll
      for (int e = 0; e < 4; ++e)
        ov[e] = geluf(acc[mt][nt][e] + Dh * xv[e]);
      *(f32x4*)&G[base] = ov;
    }
}

// ---------------- fused: y=out_w@G+out_b; GLU; +X; channel-LN -> X ----------------
__global__ __launch_bounds__(256) void k_glu(
    const float* __restrict__ G,
    const float* __restrict__ ow, const float* __restrict__ ob,
    const float* __restrict__ lng, const float* __restrict__ lnb,
    float* __restrict__ X)
{
  int b = blockIdx.y, l0 = blockIdx.x * 64;
  int t = threadIdx.x;
  __shared__ float g1[128][68];
  __shared__ float wch[256][17];
  #pragma unroll
  for (int it = 0; it < 32; ++it){
    int idx = t + it * 256;
    int ci = idx >> 6, j = idx & 63;
    g1[ci][j] = G[((size_t)b * HCH + ci) * LSEQ + l0 + j];
  }
  float acc[8][8];
  #pragma unroll
  for (int i = 0; i < 8; ++i)
    #pragma unroll
    for (int j = 0; j < 8; ++j) acc[i][j] = 0.f;
  int o0 = t & 31, lq = t >> 5;
  for (int cc = 0; cc < 8; ++cc){
    __syncthreads();
    #pragma unroll
    for (int i = 0; i < 16; ++i){
      int e = t + 256 * i;
      int o = e >> 4, cj = e & 15;
      wch[o][cj] = ow[o * 128 + cc * 16 + cj];
    }
    __syncthreads();
    #pragma unroll
    for (int cj = 0; cj < 16; ++cj){
      int ci = cc * 16 + cj;
      float xv[8];
      #pragma unroll
      for (int li = 0; li < 8; ++li) xv[li] = g1[ci][lq * 8 + li];
      #pragma unroll
      for (int oi = 0; oi < 8; ++oi){
        float wv = wch[o0 + 32 * oi][cj];
        #pragma unroll
        for (int li = 0; li < 8; ++li) acc[oi][li] = fmaf(wv, xv[li], acc[oi][li]);
      }
    }
  }
  float u[4][8];
  #pragma unroll
  for (int hi = 0; hi < 4; ++hi){
    int hch = o0 + 32 * hi;
    float ba = ob[hch], bg = ob[hch + 128];
    size_t rowo = ((size_t)b * HCH + hch) * LSEQ + l0 + (size_t)lq * 8;
    f32x4 sk0 = *(const f32x4*)&X[rowo];
    f32x4 sk1 = *(const f32x4*)&X[rowo + 4];
    #pragma unroll
    for (int li = 0; li < 8; ++li){
      float a = acc[hi][li] + ba;
      float g = acc[hi + 4][li] + bg;
      float z = a * (1.f / (1.f + expf(-g)));
      u[hi][li] = z + ((li < 4) ? sk0[li] : sk1[li - 4]);
    }
  }
  float s1[8], s2[8];
  #pragma unroll
  for (int li = 0; li < 8; ++li){
    s1[li] = u[0][li] + u[1][li] + u[2][li] + u[3][li];
    s2[li] = u[0][li] * u[0][li] + u[1][li] * u[1][li] + u[2][li] * u[2][li] + u[3][li] * u[3][li];
  }
  #pragma unroll
  for (int m = 1; m < 32; m <<= 1){
    #pragma unroll
    for (int li = 0; li < 8; ++li){
      s1[li] += __shfl_xor(s1[li], m, 64);
      s2[li] += __shfl_xor(s2[li], m, 64);
    }
  }
  float mu[8], rs[8];
  #pragma unroll
  for (int li = 0; li < 8; ++li){
    mu[li] = s1[li] * (1.f / 128.f);
    float var = s2[li] * (1.f / 128.f) - mu[li] * mu[li];
    rs[li] = rsqrtf(var + 1e-5f);
  }
  #pragma unroll
  for (int hi = 0; hi < 4; ++hi){
    int hch = o0 + 32 * hi;
    float gg = lng[hch], bb = lnb[hch];
    size_t rowo = ((size_t)b * HCH + hch) * LSEQ + l0 + (size_t)lq * 8;
    f32x4 w0, w1;
    #pragma unroll
    for (int li = 0; li < 4; ++li) w0[li] = (u[hi][li] - mu[li]) * rs[li] * gg + bb;
    #pragma unroll
    for (int li = 4; li < 8; ++li) w1[li - 4] = (u[hi][li] - mu[li]) * rs[li] * gg + bb;
    *(f32x4*)&X[rowo]     = w0;
    *(f32x4*)&X[rowo + 4] = w1;
  }
}

// ---------------- decoder as MFMA: M=16(5 used), K=1920, N=128 l-tile ----------------
__global__ __launch_bounds__(256, 1) void k_dec2(const u16* __restrict__ xTs, const u16* __restrict__ wd,
                                                 const float* __restrict__ bias, float* __restrict__ out){
  int b = blockIdx.y, l0 = blockIdx.x * 128;
  int tid = threadIdx.x, lane = tid & 63, wv = tid >> 6;
  int lan15 = lane & 15, lhi = lane >> 4;
  __shared__ alignas(16) u16 xt[144 * 128];
  __shared__ alignas(16) u16 ws[16 * 1920];
  const char* xsrc = (const char*)xTs + (size_t)b * XT_BSTRIDE + (size_t)l0 * 256;
  #pragma unroll
  for (int is = 0; is < 9; ++is){
    int off = is * 4096 + wv * 1024;
    GLDS16(xsrc + off + (lane << 4), (char*)xt + off);
  }
  #pragma unroll
  for (int is = 0; is < 15; ++is){
    int off = is * 4096 + wv * 1024;
    GLDS16((const char*)wd + off + (lane << 4), (char*)ws + off);
  }
  asm volatile("s_waitcnt vmcnt(0)" ::: "memory");
  __syncthreads();
  f32x4 acc[2] = {(f32x4){0, 0, 0, 0}, (f32x4){0, 0, 0, 0}};
  for (int k = 0; k < 15; ++k){
    #pragma unroll
    for (int ks = 0; ks < 4; ++ks){
      int K = k * 128 + ks * 32 + lhi * 8;
      short8 af = *(const short8*)((const char*)ws + lan15 * 3840 + (((u32)(K * 2)) ^ (((u32)lan15 & 7u) << 4)));
      #pragma unroll
      for (int nt = 0; nt < 2; ++nt){
        int ll = wv * 32 + nt * 16 + lan15;
        int lg = l0 + ll + k - 7;
        int row = ll + k + 1;
        short8 bf = *(const short8*)((const char*)xt + row * 256 + ((((ks * 32 + lhi * 8) * 2)) ^ ((lg & 7) << 4)));
        acc[nt] = __builtin_amdgcn_mfma_f32_16x16x32_bf16(af, bf, acc[nt], 0, 0, 0);
      }
    }
  }
  #pragma unroll
  for (int nt = 0; nt < 2; ++nt){
    int l = l0 + wv * 32 + nt * 16 + lan15;
    #pragma unroll
    for (int reg = 0; reg < 4; ++reg){
      int co = (lhi << 2) + reg;
      if (co < 5) out[((size_t)b * 5 + co) * LSEQ + l] = acc[nt][reg] + bias[co];
    }
  }
}

extern "C" void kernel_launch(void* const* d_in, const int* in_sizes, int n_in,
                              void* d_out, int out_size, void* d_ws, size_t ws_size,
                              hipStream_t stream){
  (void)in_sizes; (void)n_in; (void)out_size; (void)ws_size;
  const float* x_in   = (const float*)d_in[0];
  const float* enc_w  = (const float*)d_in[1];
  const float* enc_b  = (const float*)d_in[2];
  const float* rn_w1  = (const float*)d_in[3];
  const float* rn_b1  = (const float*)d_in[4];
  const float* rn_g1  = (const float*)d_in[5];
  const float* rn_be1 = (const float*)d_in[6];
  const float* rn_w2  = (const float*)d_in[7];
  const float* rn_b2  = (const float*)d_in[8];
  const float* rn_g2  = (const float*)d_in[9];
  const float* rn_be2 = (const float*)d_in[10];
  const float* lam_re = (const float*)d_in[11];
  const float* lam_im = (const float*)d_in[12];
  const float* log_dt = (const float*)d_in[13];
  const float* W_re   = (const float*)d_in[14];
  const float* W_im   = (const float*)d_in[15];
  const float* Dv     = (const float*)d_in[16];
  const float* out_w  = (const float*)d_in[17];
  const float* out_b  = (const float*)d_in[18];
  const float* ln_g   = (const float*)d_in[19];
  const float* ln_b   = (const float*)d_in[20];
  const float* dec_w  = (const float*)d_in[21];
  const float* dec_b  = (const float*)d_in[22];

  char* ws = (char*)d_ws;
  float* X    = (float*)(ws + 0ull);              // 64 MB residual stream
  float* PG   = (float*)(ws + 67108864ull);       // 64 MB: conv temp / P (fp32) / G (sequenced)
  u16*   Sf   = (u16*)  (ws + 134217728ull);      // 32 MB hi/lo swizzled fwd states
  u16*   Sb   = (u16*)  (ws + 167772160ull);      // 32 MB bwd states
  u16*   xTs  = (u16*)  (ws + 134217728ull);      // 33.6 MB, conv+dec phases only (aliases Sf/Sb)
  u16*   A1c  = (u16*)  (ws + 201326592ull);      // 8 MB
  u16*   A2c  = (u16*)  (ws + 209715200ull);      // 16 MB
  u16*   wswz = (u16*)  (ws + 226492416ull);      // 1.35 MB
  u16*   wdec = (u16*)  (ws + 227868672ull);      // 60 KB
  float* dssp = (float*)(ws + 227930112ull);      // 384 KB
  float* rC   = (float*)(ws + 228323328ull);      // 32 KB

  k_xpad<<<16, 256, 0, stream>>>(xTs);
  k_wxform<<<2688, 256, 0, stream>>>(rn_w1, rn_w2, wswz);
  k_wdec<<<120, 256, 0, stream>>>(dec_w, wdec);
  k_dssprep<<<64, 256, 0, stream>>>(lam_re, lam_im, log_dt, W_re, W_im, dssp);
  k_enc<<<dim3(128, 16), 128, 0, stream>>>(x_in, enc_w, enc_b, X);

  for (int r = 0; r < 3; ++r){
    k_xform<<<dim3(128, 16), 256, 0, stream>>>(X, xTs);
    k_conv<<<dim3(64, 16), 256, 0, stream>>>(xTs, (const u16*)((char*)wswz + (size_t)(2 * r) * 229376),
        rn_g1 + r * HCH, rn_b1 + r * HCH, rn_be1 + r * HCH, nullptr, PG);
    k_xform<<<dim3(128, 16), 256, 0, stream>>>(PG, xTs);
    k_conv<<<dim3(64, 16), 256, 0, stream>>>(xTs, (const u16*)((char*)wswz + (size_t)(2 * r + 1) * 229376),
        rn_g2 + r * HCH, rn_b2 + r * HCH, rn_be2 + r * HCH, X, X);
  }
  for (int dl = 0; dl < NLAY; ++dl){
    k_mats<<<128, 256, 0, stream>>>(dssp + (size_t)dl * 6 * HCH * NST, A1c, A2c, rC);
    k_dss1<<<dim3(8, 128), 256, 0, stream>>>(X, A1c, PG);
    k_scan<<<512, 256, 0, stream>>>(PG, rC, Sf, Sb);
    k_dss2<<<dim3(8, 128), 256, 0, stream>>>(X, A2c, Sf, Sb, Dv + dl * HCH, PG);
    k_glu<<<dim3(128, 16), 256, 0, stream>>>(PG, out_w + (size_t)dl * 256 * HCH, out_b + dl * 256,
        ln_g + dl * HCH, ln_b + dl * HCH, X);
  }
  k_xpad<<<16, 256, 0, stream>>>(xTs);
  k_xform<<<dim3(128, 16), 256, 0, stream>>>(X, xTs);
  k_dec2<<<dim3(64, 16), 256, 0, stream>>>(xTs, wdec, dec_b, (float*)d_out);
}

// Round 4
// 1743.750 us; speedup vs baseline: 1.9404x; 1.2562x over previous
//
#include <hip/hip_runtime.h>
#include <hip/hip_bf16.h>

// DSSResNet on MI355X.
//  enc(fp32) -> 3x { conv(MFMA bf16) x2 } -> 4x { chunked-SSM DSS (compensated bf16 MFMA) -> MFMA GLU+LN } -> dec(MFMA)
// DSS chunking (C=128): y[i] = T@x (intra) + Re(r^{i+1} Sf) + Re(r^{127-i} Sb); S via 64-step chunk scan.
// Precision: A*x = Ah*xh + Ah*xl + Al*xh (hi/lo bf16 compensation); P fp32; S hi/lo bf16.

#define BN   16
#define HCH  128
#define LSEQ 8192
#define NST  32
#define NLAY 4
#define XT_BSTRIDE 2101248ull   // 8208 rows (l=-8..8199) * 256 B per b

typedef __attribute__((ext_vector_type(4))) float f32x4;
typedef __attribute__((ext_vector_type(8))) short short8;
typedef unsigned short u16;
typedef unsigned int   u32;

struct __align__(8) U2 { u32 x, y; };
struct __align__(16) US8 { u16 v[8]; };

__device__ __forceinline__ u16 f2bf(float f){
  union { float f; u32 u; } v; v.f = f;
  u32 u = v.u;
  return (u16)((u + 0x7fffu + ((u >> 16) & 1u)) >> 16);   // RNE
}
__device__ __forceinline__ float bf2f(u32 lo16){
  union { u32 u; float f; } v; v.u = lo16 << 16; return v.f;
}
__device__ __forceinline__ float geluf(float v){
  return 0.5f * v * (1.0f + erff(v * 0.70710678118654752f));
}

#define GLDS16(g, l) \
  __builtin_amdgcn_global_load_lds((const __attribute__((address_space(1))) u32*)(g), \
                                   (__attribute__((address_space(3))) u32*)(l), 16, 0, 0)

// ---------------- zero xTs halo rows (l=-8..-1, 8192..8199) ----------------
__global__ void k_xpad(u16* xTs){
  int b = blockIdx.x, t = threadIdx.x;
  char* base = (char*)xTs + (size_t)b * XT_BSTRIDE;
  int r = t >> 4;
  int row = (r < 8) ? r : (8192 + r);          // rows 0..7 and 8200..8207
  f32x4 z = {0.f, 0.f, 0.f, 0.f};
  *(f32x4*)(base + (size_t)row * 256 + (size_t)(t & 15) * 16) = z;
}

// ---------------- resnet weights -> bf16, K-major (k*128+ci), chunked+swizzled ----------------
__global__ void k_wxform(const float* __restrict__ w1, const float* __restrict__ w2, u16* __restrict__ wswz){
  int idx = blockIdx.x * 256 + threadIdx.x;
  if (idx >= 6 * 128 * 896) return;
  int conv = idx / (128 * 896);
  int rem  = idx % (128 * 896);
  int co = rem / 896, K = rem % 896;
  int k = K >> 7, ci = K & 127;
  const float* src = (conv & 1) ? w2 : w1;
  int blk = conv >> 1;
  float v = src[(((size_t)blk * 128 + co) * 128 + ci) * 7 + k];
  int chunk = K >> 6, j = K & 63;
  size_t byteoff = (size_t)conv * 229376 + (size_t)chunk * 16384 + (size_t)co * 128
                 + (u32)((j * 2) ^ ((co & 7) << 4));
  *(u16*)((char*)wswz + byteoff) = f2bf(v);
}

// ---------------- decoder weights -> bf16 [16co][1920K] swizzled ----------------
__global__ void k_wdec(const float* __restrict__ dw, u16* __restrict__ wd){
  int idx = blockIdx.x * 256 + threadIdx.x;
  if (idx >= 16 * 1920) return;
  int co = idx / 1920, K = idx % 1920;
  int k = K >> 7, ci = K & 127;
  float v = (co < 5) ? dw[((size_t)co * 128 + ci) * 15 + k] : 0.f;
  size_t byteoff = (size_t)co * 3840 + (u32)((K * 2) ^ ((co & 7) << 4));
  *(u16*)((char*)wd + byteoff) = f2bf(v);
}

// ---------------- GLU weights: out_w -> per-layer hi/lo swizzled slices ----------------
// rows interleaved: q even = a-row (out_w[q/2]), q odd = g-row (out_w[128+q/2])
// slices a: 0=hi(k0:64) 1=hi(k64:128) 2=lo(k0:64) 3=lo(k64:128); layer stride 131072 B
__global__ void k_wglu(const float* __restrict__ ow, u16* __restrict__ wg){
  int idx = blockIdx.x * 256 + threadIdx.x;
  if (idx >= NLAY * 256 * 128) return;
  int layer = idx >> 15;
  int rem = idx & 32767;
  int q = rem >> 7, k = rem & 127;
  int row = (q & 1) ? (128 + (q >> 1)) : (q >> 1);
  float v = ow[((size_t)layer * 256 + row) * 128 + k];
  u16 hb = f2bf(v);
  u16 lb = f2bf(v - bf2f(hb));
  int a_hi = k >> 6, kk = k & 63;
  size_t base = (size_t)layer * 131072 + (size_t)q * 128 + (u32)((kk * 2) ^ ((q & 7) << 4));
  *(u16*)((char*)wg + base + (size_t)a_hi * 32768) = hb;
  *(u16*)((char*)wg + base + (size_t)(2 + a_hi) * 32768) = lb;
}

// ---------------- DSS per-layer params: r = exp(dt*Lam), Wc = W*(r-1)/Lam ----------------
__global__ void k_dssprep(const float* __restrict__ lam_re, const float* __restrict__ lam_im,
                          const float* __restrict__ log_dt, const float* __restrict__ W_re,
                          const float* __restrict__ W_im, float* __restrict__ dssp){
  int idx = blockIdx.x * 256 + threadIdx.x;
  if (idx >= NLAY * HCH * NST) return;
  int layer = idx / (HCH * NST);
  int hn = idx % (HCH * NST);
  int h = hn / NST, n = hn % NST;
  float Lre = -expf(lam_re[layer * NST + n]);
  float Lim = lam_im[layer * NST + n];
  float dt  = expf(log_dt[layer * HCH + h]);
  float are = dt * Lre, aim = dt * Lim;
  float er = expf(are);
  float rre = er * cosf(aim);
  float rim = er * sinf(aim);
  float nre = rre - 1.f, nim = rim;
  float den = 1.f / (Lre * Lre + Lim * Lim);
  float fre = (nre * Lre + nim * Lim) * den;
  float fim = (nim * Lre - nre * Lim) * den;
  float* base = dssp + (size_t)layer * 6 * HCH * NST;
  base[(0 * HCH + h) * NST + n] = rre;
  base[(1 * HCH + h) * NST + n] = rim;
  #pragma unroll
  for (int cc = 0; cc < 2; ++cc){
    float wr_ = W_re[(((size_t)layer * 2 + cc) * HCH + h) * NST + n];
    float wi_ = W_im[(((size_t)layer * 2 + cc) * HCH + h) * NST + n];
    base[((2 + 2 * cc) * HCH + h) * NST + n] = wr_ * fre - wi_ * fim;
    base[((3 + 2 * cc) * HCH + h) * NST + n] = wr_ * fim + wi_ * fre;
  }
}

// ---------------- per-layer chunk matrices (hi/lo bf16, swizzled slices) ----------------
__global__ __launch_bounds__(256) void k_mats(const float* __restrict__ pp,
                                              u16* __restrict__ A1c, u16* __restrict__ A2c,
                                              float* __restrict__ rC){
  int h = blockIdx.x, t = threadIdx.x;
  __shared__ float pre[129][33], pim[129][33];
  __shared__ float w0re[32], w0im[32], w1re[32], w1im[32];
  __shared__ float tf[128], tb[128];
  if (t < 32){
    int n = t;
    float rre = pp[(0 * HCH + h) * NST + n], rim = pp[(1 * HCH + h) * NST + n];
    w0re[n] = pp[(2 * HCH + h) * NST + n]; w0im[n] = pp[(3 * HCH + h) * NST + n];
    w1re[n] = pp[(4 * HCH + h) * NST + n]; w1im[n] = pp[(5 * HCH + h) * NST + n];
    float pr = 1.f, pi = 0.f;
    pre[0][n] = 1.f; pim[0][n] = 0.f;
    for (int p = 1; p <= 128; ++p){
      float nr = pr * rre - pi * rim;
      float ni = pr * rim + pi * rre;
      pr = nr; pi = ni;
      pre[p][n] = pr; pim[p][n] = pi;
    }
    rC[h * 64 + 2 * n] = pr; rC[h * 64 + 2 * n + 1] = pi;
  }
  __syncthreads();
  if (t < 128){
    float s = 0.f;
    for (int n = 0; n < 32; ++n) s += w0re[n] * pre[t][n] - w0im[n] * pim[t][n];
    tf[t] = s;
  } else {
    int d = t - 128;
    if (d == 0) tb[0] = 0.f;
    else {
      float s = 0.f;
      for (int n = 0; n < 32; ++n) s += w1re[n] * pre[d - 1][n] - w1im[n] * pim[d - 1][n];
      tb[d] = s;
    }
  }
  __syncthreads();
  for (int idx = t; idx < 4 * 128 * 64; idx += 256){
    int a = idx >> 13, rem = idx & 8191, q = rem >> 6, k = rem & 63;
    int j = (a & 1) * 64 + k;
    int n, p; float wr_, wi_;
    if (q < 64){ n = q >> 1; p = 127 - j; wr_ = w0re[n]; wi_ = w0im[n]; }
    else       { n = (q - 64) >> 1; p = j; wr_ = w1re[n]; wi_ = w1im[n]; }
    float pr = pre[p][n], pi = pim[p][n];
    float v = (q & 1) ? (wr_ * pi + wi_ * pr) : (wr_ * pr - wi_ * pi);
    u16 hb = f2bf(v);
    u16 ob = (a < 2) ? hb : f2bf(v - bf2f(hb));
    *(u16*)((char*)A1c + (size_t)h * 65536 + (size_t)a * 16384 + (size_t)q * 128
            + (u32)((k * 2) ^ ((q & 7) << 4))) = ob;
  }
  for (int idx = t; idx < 8 * 128 * 64; idx += 256){
    int a = idx >> 13, rem = idx & 8191, i = rem >> 6, k = rem & 63;
    float v; bool lo;
    if (a < 4){
      int colT = (a & 1) * 64 + k;
      v = (i >= colT) ? tf[i - colT] : tb[colT - i];
      lo = (a >= 2);
    } else {
      int n = k >> 1;
      int p = (a < 6) ? (i + 1) : (127 - i);
      v = (k & 1) ? -pim[p][n] : pre[p][n];
      lo = (a == 5) || (a == 7);
    }
    u16 hb = f2bf(v);
    u16 ob = lo ? f2bf(v - bf2f(hb)) : hb;
    *(u16*)((char*)A2c + (size_t)h * 131072 + (size_t)a * 16384 + (size_t)i * 128
            + (u32)((k * 2) ^ ((i & 7) << 4))) = ob;
  }
}

// ---------------- encoder conv: (B,5,L) -> (B,128,L), K=15 'same', fp32 ----------------
__global__ __launch_bounds__(128) void k_enc(const float* __restrict__ xin, const float* __restrict__ w,
                                             const float* __restrict__ bias, float* __restrict__ X){
  int b = blockIdx.y, l0 = blockIdx.x * 64;
  int t = threadIdx.x;                       // t = co
  __shared__ float xs[5][78];
  for (int i = t; i < 5 * 78; i += 128){
    int ci = i / 78, j = i % 78;
    int l = l0 - 7 + j;
    xs[ci][j] = (l >= 0 && l < LSEQ) ? xin[((size_t)b * 5 + ci) * LSEQ + l] : 0.f;
  }
  float wreg[75];
  #pragma unroll
  for (int i = 0; i < 75; ++i) wreg[i] = w[t * 75 + i];
  float bc = bias[t];
  __syncthreads();
  size_t orow = ((size_t)b * HCH + t) * LSEQ + l0;
  for (int gb = 0; gb < 8; ++gb){
    float acc[8] = {0, 0, 0, 0, 0, 0, 0, 0};
    #pragma unroll
    for (int ci = 0; ci < 5; ++ci){
      #pragma unroll
      for (int k = 0; k < 15; ++k){
        float wv = wreg[ci * 15 + k];
        #pragma unroll
        for (int j = 0; j < 8; ++j)
          acc[j] = fmaf(wv, xs[ci][gb * 8 + j + k], acc[j]);
      }
    }
    f32x4 o0 = {acc[0] + bc, acc[1] + bc, acc[2] + bc, acc[3] + bc};
    f32x4 o1 = {acc[4] + bc, acc[5] + bc, acc[6] + bc, acc[7] + bc};
    *(f32x4*)&X[orow + gb * 8]     = o0;
    *(f32x4*)&X[orow + gb * 8 + 4] = o1;
  }
}

// ---------------- X (b,h,l) fp32 -> xTs (b,l,ci) bf16, row-swizzled by (l&7) ----------------
__global__ __launch_bounds__(256) void k_xform(const float* __restrict__ Xin, u16* __restrict__ xTs){
  int b = blockIdx.y, l0 = blockIdx.x * 64;
  int t = threadIdx.x;
  __shared__ float tile[128][65];
  #pragma unroll
  for (int it = 0; it < 32; ++it){
    int idx = t + it * 256;
    int ci = idx >> 6, j = idx & 63;
    tile[ci][j] = Xin[((size_t)b * HCH + ci) * LSEQ + l0 + j];
  }
  __syncthreads();
  int rl = t >> 2, q = t & 3;
  int l = l0 + rl;
  char* rowp = (char*)xTs + (size_t)b * XT_BSTRIDE + (size_t)(l + 8) * 256;
  u32 key = ((u32)l & 7u) << 4;
  #pragma unroll
  for (int ii = 0; ii < 8; ++ii){
    int c0 = q * 32 + ii * 4;
    U2 val;
    val.x = (u32)f2bf(tile[c0 + 0][rl]) | ((u32)f2bf(tile[c0 + 1][rl]) << 16);
    val.y = (u32)f2bf(tile[c0 + 2][rl]) | ((u32)f2bf(tile[c0 + 3][rl]) << 16);
    *(U2*)(rowp + (((u32)(c0 * 2)) ^ key)) = val;
  }
}

// ---------------- resnet conv (K=7) as MFMA GEMM ----------------
__global__ __launch_bounds__(256, 2) void k_conv(
    const u16* __restrict__ xTs, const u16* __restrict__ wcv,
    const float* __restrict__ bng, const float* __restrict__ bnb, const float* __restrict__ bnbe,
    const float* __restrict__ Xres, float* __restrict__ Xout)
{
  int b = blockIdx.y, l0 = blockIdx.x * 128;
  int tid = threadIdx.x, lane = tid & 63, wv = tid >> 6;
  int wr = wv >> 1, wc = wv & 1;
  int lan15 = lane & 15, lhi = lane >> 4;

  __shared__ alignas(16) u16 xt[144 * 128];
  __shared__ alignas(16) u16 wch[2][128 * 64];

  const char* xsrc = (const char*)xTs + (size_t)b * XT_BSTRIDE + (size_t)l0 * 256;
  #pragma unroll
  for (int is = 0; is < 9; ++is){
    int off = is * 4096 + wv * 1024;
    GLDS16(xsrc + off + (lane << 4), (char*)xt + off);
  }
  {
    const char* wsrc = (const char*)wcv;
    #pragma unroll
    for (int is = 0; is < 4; ++is){
      int off = is * 4096 + wv * 1024;
      GLDS16(wsrc + off + (lane << 4), (char*)&wch[0][0] + off);
    }
  }
  asm volatile("s_waitcnt vmcnt(0)" ::: "memory");
  __syncthreads();

  f32x4 acc[4][4];
  #pragma unroll
  for (int i = 0; i < 4; ++i)
    #pragma unroll
    for (int j = 0; j < 4; ++j) acc[i][j] = (f32x4){0.f, 0.f, 0.f, 0.f};

  for (int c = 0; c < 14; ++c){
    int cur = c & 1;
    if (c < 13){
      const char* wsrc = (const char*)wcv + (size_t)(c + 1) * 16384;
      #pragma unroll
      for (int is = 0; is < 4; ++is){
        int off = is * 4096 + wv * 1024;
        GLDS16(wsrc + off + (lane << 4), (char*)&wch[cur ^ 1][0] + off);
      }
    }
    int k = c >> 1;
    const char* wb = (const char*)&wch[cur][0];
    #pragma unroll
    for (int ks = 0; ks < 2; ++ks){
      short8 af[4], bf[4];
      int j0 = ks * 32 + lhi * 8;
      #pragma unroll
      for (int mt = 0; mt < 4; ++mt){
        int co = wr * 64 + mt * 16 + lan15;
        af[mt] = *(const short8*)(wb + co * 128 + ((j0 * 2) ^ ((co & 7) << 4)));
      }
      int ci0 = (c & 1) * 64 + ks * 32 + lhi * 8;
      #pragma unroll
      for (int nt = 0; nt < 4; ++nt){
        int ll = wc * 64 + nt * 16 + lan15;
        int row = ll + k + 5;                  // staged row of source l = l0+ll+k-3 (halo 8)
        int lg = l0 + ll + k - 3;
        bf[nt] = *(const short8*)((const char*)xt + row * 256 + ((ci0 * 2) ^ ((lg & 7) << 4)));
      }
      #pragma unroll
      for (int mt = 0; mt < 4; ++mt)
        #pragma unroll
        for (int nt = 0; nt < 4; ++nt)
          acc[mt][nt] = __builtin_amdgcn_mfma_f32_16x16x32_bf16(af[mt], bf[nt], acc[mt][nt], 0, 0, 0);
    }
    asm volatile("s_waitcnt vmcnt(0)" ::: "memory");
    __syncthreads();
  }

  bool hasres = (Xres != nullptr);
  #pragma unroll
  for (int mt = 0; mt < 4; ++mt){
    #pragma unroll
    for (int reg = 0; reg < 4; ++reg){
      int co = wr * 64 + mt * 16 + (lhi << 2) + reg;
      float A = bng[co] * 0.99999500003749968f;
      float Bc = fmaf(bnb[co], A, bnbe[co]);
      size_t rowb = ((size_t)b * HCH + co) * LSEQ;
      #pragma unroll
      for (int nt = 0; nt < 4; ++nt){
        int l = l0 + wc * 64 + nt * 16 + lan15;
        float v = fmaf(acc[mt][nt][reg], A, Bc);
        if (hasres) v += Xres[rowb + l];
        v = fmaxf(v, 0.f);
        Xout[rowb + l] = v;
      }
    }
  }
}

// ---------------- stage x tile (hi/lo bf16) into LDS: [128 col][128 k], col=(c&7)*16+b ----------------
__device__ __forceinline__ void stage_x_tile(const float* __restrict__ X, int h, int ct,
                                             char* xh, char* xl, int t){
  int k8 = t & 15;            // k-group: k = k8*8
  int c0 = t >> 4;            // base col
  #pragma unroll
  for (int it = 0; it < 8; ++it){
    int col = c0 + it * 16;
    int c = ct * 8 + (col >> 4), b = col & 15;
    const float* src = X + ((size_t)b * HCH + h) * LSEQ + (size_t)c * 128 + k8 * 8;
    f32x4 v0 = *(const f32x4*)src;
    f32x4 v1 = *(const f32x4*)(src + 4);
    US8 hi, lo;
    #pragma unroll
    for (int e = 0; e < 4; ++e){
      u16 hb = f2bf(v0[e]);
      hi.v[e] = hb; lo.v[e] = f2bf(v0[e] - bf2f(hb));
      u16 hb2 = f2bf(v1[e]);
      hi.v[e + 4] = hb2; lo.v[e + 4] = f2bf(v1[e] - bf2f(hb2));
    }
    u32 off = (u32)col * 256 + (u32)((k8 * 16) ^ ((col & 7) << 4));
    *(US8*)(xh + off) = hi;
    *(US8*)(xl + off) = lo;
  }
}

// ---------------- GEMM1: P[128q][col] = A1h@xh + A1h@xl + A1l@xh (per h,ct) ----------------
__global__ __launch_bounds__(256) void k_dss1(const float* __restrict__ X,
                                              const u16* __restrict__ A1c,
                                              float* __restrict__ P){
  int ct = blockIdx.x, h = blockIdx.y;
  int tid = threadIdx.x, lane = tid & 63, wv = tid >> 6;
  int wr = wv >> 1, wc = wv & 1, lan15 = lane & 15, lhi = lane >> 4;
  __shared__ alignas(16) u16 bx[32768];      // xh [0,32KB) xl [32KB,64KB)
  __shared__ alignas(16) u16 ach[2][8192];

  stage_x_tile(X, h, ct, (char*)bx, (char*)bx + 32768, tid);
  const char* abase = (const char*)A1c + (size_t)h * 65536;
  #pragma unroll
  for (int is = 0; is < 4; ++is){
    int off = is * 4096 + wv * 1024;
    GLDS16(abase + off + (lane << 4), (char*)&ach[0][0] + off);
  }
  asm volatile("s_waitcnt vmcnt(0)" ::: "memory");
  __syncthreads();

  f32x4 acc[4][4];
  #pragma unroll
  for (int i = 0; i < 4; ++i)
    #pragma unroll
    for (int j = 0; j < 4; ++j) acc[i][j] = (f32x4){0.f, 0.f, 0.f, 0.f};

  const int asel[6] = {0, 1, 0, 1, 2, 3};
  const int bsel[6] = {0, 0, 1, 1, 0, 0};
  const int bk0 [6] = {0, 64, 0, 64, 0, 64};
  #pragma unroll
  for (int s = 0; s < 6; ++s){
    if (s < 5){
      const char* an = abase + (size_t)asel[s + 1] * 16384;
      #pragma unroll
      for (int is = 0; is < 4; ++is){
        int off = is * 4096 + wv * 1024;
        GLDS16(an + off + (lane << 4), (char*)&ach[(s + 1) & 1][0] + off);
      }
    }
    const char* bt = (const char*)bx + bsel[s] * 32768;
    const char* at = (const char*)&ach[s & 1][0];
    #pragma unroll
    for (int ks = 0; ks < 2; ++ks){
      int ka = ks * 32 + lhi * 8;
      short8 af[4], bf[4];
      #pragma unroll
      for (int mt = 0; mt < 4; ++mt){
        int q = wr * 64 + mt * 16 + lan15;
        af[mt] = *(const short8*)(at + q * 128 + ((ka * 2) ^ ((q & 7) << 4)));
      }
      int kb = bk0[s] + ka;
      #pragma unroll
      for (int nt = 0; nt < 4; ++nt){
        int col = wc * 64 + nt * 16 + lan15;
        bf[nt] = *(const short8*)(bt + col * 256 + ((kb * 2) ^ ((col & 7) << 4)));
      }
      #pragma unroll
      for (int mt = 0; mt < 4; ++mt)
        #pragma unroll
        for (int nt = 0; nt < 4; ++nt)
          acc[mt][nt] = __builtin_amdgcn_mfma_f32_16x16x32_bf16(af[mt], bf[nt], acc[mt][nt], 0, 0, 0);
    }
    asm volatile("s_waitcnt vmcnt(0)" ::: "memory");
    __syncthreads();
  }

  #pragma unroll
  for (int mt = 0; mt < 4; ++mt)
    #pragma unroll
    for (int nt = 0; nt < 4; ++nt){
      int col = ct * 128 + wc * 64 + nt * 16 + lan15;
      int q0 = wr * 64 + mt * 16 + (lhi << 2);
      *(f32x4*)&P[((size_t)h * 1024 + col) * 128 + q0] = acc[mt][nt];
    }
}

// ---------------- chunk scan (fp32): S[c] written (hi/lo bf16, swizzled) before update ----------------
__global__ __launch_bounds__(256) void k_scan(const float* __restrict__ P,
                                              const float* __restrict__ rC,
                                              u16* __restrict__ Sf, u16* __restrict__ Sb){
  int part = blockIdx.x & 3, h = blockIdx.x >> 2;
  int t = threadIdx.x;
  int dir = part >> 1;
  int b = (part & 1) * 8 + (t >> 5);
  int n = t & 31;
  float rre = rC[h * 64 + 2 * n], rim = rC[h * 64 + 2 * n + 1];
  u16* SO = dir ? Sb : Sf;
  const float* pbase = P + (size_t)h * 131072 + (size_t)b * 128 + dir * 64 + 2 * n;
  float sre = 0.f, sim = 0.f;
  u32 key = ((u32)b & 7u) << 4;
  for (int ii = 0; ii < 64; ++ii){
    int c = dir ? (63 - ii) : ii;
    u16 hr = f2bf(sre), hm = f2bf(sim);
    u32 hw = (u32)hr | ((u32)hm << 16);
    u32 lw = (u32)f2bf(sre - bf2f(hr)) | ((u32)f2bf(sim - bf2f(hm)) << 16);
    char* sp = (char*)SO + ((size_t)(h * 8 + (c >> 3)) * 2) * 16384
             + (size_t)((c & 7) * 16 + b) * 128 + (u32)((4 * n) ^ key);
    *(u32*)sp = hw;
    *(u32*)(sp + 16384) = lw;
    const float* pp = pbase + (size_t)c * 2048;
    float pr = pp[0], pi = pp[1];
    float nr = rre * sre - rim * sim + pr;
    float ni = rre * sim + rim * sre + pi;
    sre = nr; sim = ni;
  }
}

// ---------------- GEMM2: Y = T@x + Vf@Sf + Vb@Sb (compensated); G = gelu(Y + D*x) ----------------
__global__ __launch_bounds__(256) void k_dss2(const float* __restrict__ X,
                                              const u16* __restrict__ A2c,
                                              const u16* __restrict__ Sf,
                                              const u16* __restrict__ Sb,
                                              const float* __restrict__ Dv,
                                              float* __restrict__ G){
  int ct = blockIdx.x, h = blockIdx.y;
  int tid = threadIdx.x, lane = tid & 63, wv = tid >> 6;
  int wr = wv >> 1, wc = wv & 1, lan15 = lane & 15, lhi = lane >> 4;
  __shared__ alignas(16) u16 bx[32768];      // phase T: xh|xl ; phase V: Sfh|Sfl|Sbh|Sbl (4x16KB)
  __shared__ alignas(16) u16 ach[2][8192];

  stage_x_tile(X, h, ct, (char*)bx, (char*)bx + 32768, tid);
  const char* abase = (const char*)A2c + (size_t)h * 131072;
  #pragma unroll
  for (int is = 0; is < 4; ++is){
    int off = is * 4096 + wv * 1024;
    GLDS16(abase + off + (lane << 4), (char*)&ach[0][0] + off);
  }
  asm volatile("s_waitcnt vmcnt(0)" ::: "memory");
  __syncthreads();

  f32x4 acc[4][4];
  #pragma unroll
  for (int i = 0; i < 4; ++i)
    #pragma unroll
    for (int j = 0; j < 4; ++j) acc[i][j] = (f32x4){0.f, 0.f, 0.f, 0.f};

  // ---- phase T: [Th|Th|Tl] x [xh;xl;xh] ----
  {
    const int asel[6] = {0, 1, 0, 1, 2, 3};
    const int bsel[6] = {0, 0, 1, 1, 0, 0};
    const int bk0 [6] = {0, 64, 0, 64, 0, 64};
    #pragma unroll
    for (int s = 0; s < 6; ++s){
      if (s < 5){
        const char* an = abase + (size_t)asel[s + 1] * 16384;
        #pragma unroll
        for (int is = 0; is < 4; ++is){
          int off = is * 4096 + wv * 1024;
          GLDS16(an + off + (lane << 4), (char*)&ach[(s + 1) & 1][0] + off);
        }
      }
      const char* bt = (const char*)bx + bsel[s] * 32768;
      const char* at = (const char*)&ach[s & 1][0];
      #pragma unroll
      for (int ks = 0; ks < 2; ++ks){
        int ka = ks * 32 + lhi * 8;
        short8 af[4], bf[4];
        #pragma unroll
        for (int mt = 0; mt < 4; ++mt){
          int i = wr * 64 + mt * 16 + lan15;
          af[mt] = *(const short8*)(at + i * 128 + ((ka * 2) ^ ((i & 7) << 4)));
        }
        int kb = bk0[s] + ka;
        #pragma unroll
        for (int nt = 0; nt < 4; ++nt){
          int col = wc * 64 + nt * 16 + lan15;
          bf[nt] = *(const short8*)(bt + col * 256 + ((kb * 2) ^ ((col & 7) << 4)));
        }
        #pragma unroll
        for (int mt = 0; mt < 4; ++mt)
          #pragma unroll
          for (int nt = 0; nt < 4; ++nt)
            acc[mt][nt] = __builtin_amdgcn_mfma_f32_16x16x32_bf16(af[mt], bf[nt], acc[mt][nt], 0, 0, 0);
      }
      asm volatile("s_waitcnt vmcnt(0)" ::: "memory");
      __syncthreads();
    }
  }
  // ---- boundary: restage B with S tiles + A slice 4 ----
  {
    const char* st0 = (const char*)Sf + ((size_t)(h * 8 + ct) * 2) * 16384;
    const char* st2 = (const char*)Sb + ((size_t)(h * 8 + ct) * 2) * 16384;
    const char* stile[4] = {st0, st0 + 16384, st2, st2 + 16384};
    #pragma unroll
    for (int tt = 0; tt < 4; ++tt){
      #pragma unroll
      for (int is = 0; is < 4; ++is){
        int off = is * 4096 + wv * 1024;
        GLDS16(stile[tt] + off + (lane << 4), (char*)bx + tt * 16384 + off);
      }
    }
    const char* an = abase + 4 * 16384;
    #pragma unroll
    for (int is = 0; is < 4; ++is){
      int off = is * 4096 + wv * 1024;
      GLDS16(an + off + (lane << 4), (char*)&ach[0][0] + off);
    }
    asm volatile("s_waitcnt vmcnt(0)" ::: "memory");
    __syncthreads();
  }
  // ---- phase V: Vfh*Sfh + Vfh*Sfl + Vfl*Sfh + Vbh*Sbh + Vbh*Sbl + Vbl*Sbh ----
  {
    const int asel[6] = {4, 4, 5, 6, 6, 7};
    const int bof [6] = {0, 16384, 0, 32768, 49152, 32768};
    #pragma unroll
    for (int s = 0; s < 6; ++s){
      if (s < 5){
        const char* an = abase + (size_t)asel[s + 1] * 16384;
        #pragma unroll
        for (int is = 0; is < 4; ++is){
          int off = is * 4096 + wv * 1024;
          GLDS16(an + off + (lane << 4), (char*)&ach[(s + 1) & 1][0] + off);
        }
      }
      const char* bt = (const char*)bx + bof[s];
      const char* at = (const char*)&ach[s & 1][0];
      #pragma unroll
      for (int ks = 0; ks < 2; ++ks){
        int ka = ks * 32 + lhi * 8;
        short8 af[4], bf[4];
        #pragma unroll
        for (int mt = 0; mt < 4; ++mt){
          int i = wr * 64 + mt * 16 + lan15;
          af[mt] = *(const short8*)(at + i * 128 + ((ka * 2) ^ ((i & 7) << 4)));
        }
        #pragma unroll
        for (int nt = 0; nt < 4; ++nt){
          int col = wc * 64 + nt * 16 + lan15;
          bf[nt] = *(const short8*)(bt + col * 128 + ((ka * 2) ^ ((col & 7) << 4)));
        }
        #pragma unroll
        for (int mt = 0; mt < 4; ++mt)
          #pragma unroll
          for (int nt = 0; nt < 4; ++nt)
            acc[mt][nt] = __builtin_amdgcn_mfma_f32_16x16x32_bf16(af[mt], bf[nt], acc[mt][nt], 0, 0, 0);
      }
      asm volatile("s_waitcnt vmcnt(0)" ::: "memory");
      __syncthreads();
    }
  }
  // ---- epilogue: G = gelu(Y + D*x), fp32 ----
  float Dh = Dv[h];
  #pragma unroll
  for (int mt = 0; mt < 4; ++mt)
    #pragma unroll
    for (int nt = 0; nt < 4; ++nt){
      int col = wc * 64 + nt * 16 + lan15;
      int c = ct * 8 + (col >> 4), b = col & 15;
      int i0 = wr * 64 + mt * 16 + (lhi << 2);
      size_t base = ((size_t)b * HCH + h) * LSEQ + (size_t)c * 128 + i0;
      f32x4 xv = *(const f32x4*)&X[base];
      f32x4 ov;
      #pragma unroll
      for (int e = 0; e < 4; ++e)
        ov[e] = geluf(acc[mt][nt][e] + Dh * xv[e]);
      *(f32x4*)&G[base] = ov;
    }
}

// ---------------- MFMA GLU+LN: y = Wg @ G (compensated); z=a*sig(g); u=z+X; LN -> X ----------------
// M=256 interleaved rows (q=2o a, q=2o+1 g), N=64 l-cols per block, K=128 (h)
__global__ __launch_bounds__(256) void k_glu2(
    const float* __restrict__ G,
    const u16* __restrict__ Wg,      // layer slices: [256 q][64 k] x {hi0,hi1,lo0,lo1}
    const float* __restrict__ ob,
    const float* __restrict__ lng, const float* __restrict__ lnb,
    float* __restrict__ X)
{
  int b = blockIdx.y, l0 = blockIdx.x * 64;
  int tid = threadIdx.x, lane = tid & 63, wv = tid >> 6;
  int lan15 = lane & 15, lhi = lane >> 4;
  __shared__ alignas(16) u16 gt[2][64 * 128];   // hi/lo : [col l][128 h], swizzled by (l&7)<<4
  __shared__ alignas(16) u16 ach[256 * 64];     // A slice 32 KB
  __shared__ float lnbuf[4][64][2];

  // ---- stage G transposed, hi/lo split ----
  {
    int hp = tid & 63, lgrp = tid >> 6;
    const float* g0 = G + ((size_t)b * HCH + 2 * hp) * LSEQ + l0 + lgrp * 16;
    const float* g1 = g0 + LSEQ;
    #pragma unroll
    for (int j4 = 0; j4 < 4; ++j4){
      f32x4 r0 = *(const f32x4*)(g0 + j4 * 4);
      f32x4 r1 = *(const f32x4*)(g1 + j4 * 4);
      #pragma unroll
      for (int e = 0; e < 4; ++e){
        int l = lgrp * 16 + j4 * 4 + e;
        u16 h0 = f2bf(r0[e]), h1 = f2bf(r1[e]);
        u16 q0 = f2bf(r0[e] - bf2f(h0)), q1 = f2bf(r1[e] - bf2f(h1));
        u32 off = (u32)l * 256 + (((u32)hp * 4) ^ (((u32)l & 7u) << 4));
        *(u32*)((char*)&gt[0][0] + off) = (u32)h0 | ((u32)h1 << 16);
        *(u32*)((char*)&gt[1][0] + off) = (u32)q0 | ((u32)q1 << 16);
      }
    }
  }

  f32x4 acc[4][4];
  #pragma unroll
  for (int i = 0; i < 4; ++i)
    #pragma unroll
    for (int j = 0; j < 4; ++j) acc[i][j] = (f32x4){0.f, 0.f, 0.f, 0.f};

  const int asel[6] = {0, 1, 0, 1, 2, 3};
  const int bsel[6] = {0, 0, 1, 1, 0, 0};
  const int bk0 [6] = {0, 64, 0, 64, 0, 64};
  for (int s = 0; s < 6; ++s){
    __syncthreads();                               // prior pass done reading ach / gt writes done
    const char* an = (const char*)Wg + (size_t)asel[s] * 32768;
    #pragma unroll
    for (int is = 0; is < 8; ++is){
      int off = is * 4096 + wv * 1024;
      GLDS16(an + off + (lane << 4), (char*)ach + off);
    }
    asm volatile("s_waitcnt vmcnt(0)" ::: "memory");
    __syncthreads();
    const char* bt = (const char*)&gt[bsel[s]][0];
    #pragma unroll
    for (int ks = 0; ks < 2; ++ks){
      int ka = ks * 32 + lhi * 8;
      short8 af[4], bf[4];
      #pragma unroll
      for (int mt = 0; mt < 4; ++mt){
        int q = wv * 64 + mt * 16 + lan15;
        af[mt] = *(const short8*)((const char*)ach + q * 128 + ((ka * 2) ^ ((q & 7) << 4)));
      }
      int kb = bk0[s] + ka;
      #pragma unroll
      for (int nt = 0; nt < 4; ++nt){
        int col = nt * 16 + lan15;
        bf[nt] = *(const short8*)(bt + col * 256 + ((kb * 2) ^ ((col & 7) << 4)));
      }
      #pragma unroll
      for (int mt = 0; mt < 4; ++mt)
        #pragma unroll
        for (int nt = 0; nt < 4; ++nt)
          acc[mt][nt] = __builtin_amdgcn_mfma_f32_16x16x32_bf16(af[mt], bf[nt], acc[mt][nt], 0, 0, 0);
    }
  }

  // ---- GLU + skip; stash u in acc[..][2e]; partial LN sums ----
  float s1v[4] = {0, 0, 0, 0}, s2v[4] = {0, 0, 0, 0};
  float oba[4][2], obg[4][2];
  #pragma unroll
  for (int mt = 0; mt < 4; ++mt)
    #pragma unroll
    for (int e = 0; e < 2; ++e){
      int o = wv * 32 + mt * 8 + lhi * 2 + e;
      oba[mt][e] = ob[o]; obg[mt][e] = ob[o + 128];
    }
  #pragma unroll
  for (int nt = 0; nt < 4; ++nt){
    int l = l0 + nt * 16 + lan15;
    #pragma unroll
    for (int mt = 0; mt < 4; ++mt){
      #pragma unroll
      for (int e = 0; e < 2; ++e){
        int o = wv * 32 + mt * 8 + lhi * 2 + e;
        float a = acc[mt][nt][2 * e]     + oba[mt][e];
        float g = acc[mt][nt][2 * e + 1] + obg[mt][e];
        float z = a * (1.f / (1.f + expf(-g)));
        float u = z + X[((size_t)b * HCH + o) * LSEQ + l];
        acc[mt][nt][2 * e] = u;
        s1v[nt] += u; s2v[nt] += u * u;
      }
    }
  }
  #pragma unroll
  for (int nt = 0; nt < 4; ++nt){
    s1v[nt] += __shfl_xor(s1v[nt], 16, 64);
    s1v[nt] += __shfl_xor(s1v[nt], 32, 64);
    s2v[nt] += __shfl_xor(s2v[nt], 16, 64);
    s2v[nt] += __shfl_xor(s2v[nt], 32, 64);
  }
  if (lhi == 0){
    #pragma unroll
    for (int nt = 0; nt < 4; ++nt){
      lnbuf[wv][nt * 16 + lan15][0] = s1v[nt];
      lnbuf[wv][nt * 16 + lan15][1] = s2v[nt];
    }
  }
  __syncthreads();
  #pragma unroll
  for (int nt = 0; nt < 4; ++nt){
    int col = nt * 16 + lan15;
    float S1 = lnbuf[0][col][0] + lnbuf[1][col][0] + lnbuf[2][col][0] + lnbuf[3][col][0];
    float S2 = lnbuf[0][col][1] + lnbuf[1][col][1] + lnbuf[2][col][1] + lnbuf[3][col][1];
    float mu = S1 * (1.f / 128.f);
    float var = S2 * (1.f / 128.f) - mu * mu;
    float rs = rsqrtf(var + 1e-5f);
    int l = l0 + col;
    #pragma unroll
    for (int mt = 0; mt < 4; ++mt)
      #pragma unroll
      for (int e = 0; e < 2; ++e){
        int o = wv * 32 + mt * 8 + lhi * 2 + e;
        float u = acc[mt][nt][2 * e];
        X[((size_t)b * HCH + o) * LSEQ + l] = (u - mu) * rs * lng[o] + lnb[o];
      }
  }
}

// ---------------- decoder as MFMA: M=16(5 used), K=1920, N=128 l-tile ----------------
__global__ __launch_bounds__(256, 1) void k_dec2(const u16* __restrict__ xTs, const u16* __restrict__ wd,
                                                 const float* __restrict__ bias, float* __restrict__ out){
  int b = blockIdx.y, l0 = blockIdx.x * 128;
  int tid = threadIdx.x, lane = tid & 63, wv = tid >> 6;
  int lan15 = lane & 15, lhi = lane >> 4;
  __shared__ alignas(16) u16 xt[144 * 128];
  __shared__ alignas(16) u16 ws[16 * 1920];
  const char* xsrc = (const char*)xTs + (size_t)b * XT_BSTRIDE + (size_t)l0 * 256;
  #pragma unroll
  for (int is = 0; is < 9; ++is){
    int off = is * 4096 + wv * 1024;
    GLDS16(xsrc + off + (lane << 4), (char*)xt + off);
  }
  #pragma unroll
  for (int is = 0; is < 15; ++is){
    int off = is * 4096 + wv * 1024;
    GLDS16((const char*)wd + off + (lane << 4), (char*)ws + off);
  }
  asm volatile("s_waitcnt vmcnt(0)" ::: "memory");
  __syncthreads();
  f32x4 acc[2] = {(f32x4){0, 0, 0, 0}, (f32x4){0, 0, 0, 0}};
  for (int k = 0; k < 15; ++k){
    #pragma unroll
    for (int ks = 0; ks < 4; ++ks){
      int K = k * 128 + ks * 32 + lhi * 8;
      short8 af = *(const short8*)((const char*)ws + lan15 * 3840 + (((u32)(K * 2)) ^ (((u32)lan15 & 7u) << 4)));
      #pragma unroll
      for (int nt = 0; nt < 2; ++nt){
        int ll = wv * 32 + nt * 16 + lan15;
        int lg = l0 + ll + k - 7;
        int row = ll + k + 1;
        short8 bf = *(const short8*)((const char*)xt + row * 256 + ((((ks * 32 + lhi * 8) * 2)) ^ ((lg & 7) << 4)));
        acc[nt] = __builtin_amdgcn_mfma_f32_16x16x32_bf16(af, bf, acc[nt], 0, 0, 0);
      }
    }
  }
  #pragma unroll
  for (int nt = 0; nt < 2; ++nt){
    int l = l0 + wv * 32 + nt * 16 + lan15;
    #pragma unroll
    for (int reg = 0; reg < 4; ++reg){
      int co = (lhi << 2) + reg;
      if (co < 5) out[((size_t)b * 5 + co) * LSEQ + l] = acc[nt][reg] + bias[co];
    }
  }
}

extern "C" void kernel_launch(void* const* d_in, const int* in_sizes, int n_in,
                              void* d_out, int out_size, void* d_ws, size_t ws_size,
                              hipStream_t stream){
  (void)in_sizes; (void)n_in; (void)out_size; (void)ws_size;
  const float* x_in   = (const float*)d_in[0];
  const float* enc_w  = (const float*)d_in[1];
  const float* enc_b  = (const float*)d_in[2];
  const float* rn_w1  = (const float*)d_in[3];
  const float* rn_b1  = (const float*)d_in[4];
  const float* rn_g1  = (const float*)d_in[5];
  const float* rn_be1 = (const float*)d_in[6];
  const float* rn_w2  = (const float*)d_in[7];
  const float* rn_b2  = (const float*)d_in[8];
  const float* rn_g2  = (const float*)d_in[9];
  const float* rn_be2 = (const float*)d_in[10];
  const float* lam_re = (const float*)d_in[11];
  const float* lam_im = (const float*)d_in[12];
  const float* log_dt = (const float*)d_in[13];
  const float* W_re   = (const float*)d_in[14];
  const float* W_im   = (const float*)d_in[15];
  const float* Dv     = (const float*)d_in[16];
  const float* out_w  = (const float*)d_in[17];
  const float* out_b  = (const float*)d_in[18];
  const float* ln_g   = (const float*)d_in[19];
  const float* ln_b   = (const float*)d_in[20];
  const float* dec_w  = (const float*)d_in[21];
  const float* dec_b  = (const float*)d_in[22];

  char* ws = (char*)d_ws;
  float* X    = (float*)(ws + 0ull);              // 64 MB residual stream
  float* PG   = (float*)(ws + 67108864ull);       // 64 MB: conv temp / P (fp32) / G (sequenced)
  u16*   Sf   = (u16*)  (ws + 134217728ull);      // 32 MB hi/lo swizzled fwd states
  u16*   Sb   = (u16*)  (ws + 167772160ull);      // 32 MB bwd states
  u16*   xTs  = (u16*)  (ws + 134217728ull);      // 33.6 MB, conv+dec phases only (aliases Sf/Sb)
  u16*   A1c  = (u16*)  (ws + 201326592ull);      // 8 MB
  u16*   A2c  = (u16*)  (ws + 209715200ull);      // 16 MB
  u16*   wswz = (u16*)  (ws + 226492416ull);      // 1.35 MB
  u16*   wdec = (u16*)  (ws + 227868672ull);      // 60 KB
  float* dssp = (float*)(ws + 227930112ull);      // 384 KB
  float* rC   = (float*)(ws + 228323328ull);      // 32 KB
  u16*   wglu = (u16*)  (ws + 228356096ull);      // 512 KB (4 layers x 131072 B)

  k_xpad<<<16, 256, 0, stream>>>(xTs);
  k_wxform<<<2688, 256, 0, stream>>>(rn_w1, rn_w2, wswz);
  k_wdec<<<120, 256, 0, stream>>>(dec_w, wdec);
  k_wglu<<<512, 256, 0, stream>>>(out_w, wglu);
  k_dssprep<<<64, 256, 0, stream>>>(lam_re, lam_im, log_dt, W_re, W_im, dssp);
  k_enc<<<dim3(128, 16), 128, 0, stream>>>(x_in, enc_w, enc_b, X);

  for (int r = 0; r < 3; ++r){
    k_xform<<<dim3(128, 16), 256, 0, stream>>>(X, xTs);
    k_conv<<<dim3(64, 16), 256, 0, stream>>>(xTs, (const u16*)((char*)wswz + (size_t)(2 * r) * 229376),
        rn_g1 + r * HCH, rn_b1 + r * HCH, rn_be1 + r * HCH, nullptr, PG);
    k_xform<<<dim3(128, 16), 256, 0, stream>>>(PG, xTs);
    k_conv<<<dim3(64, 16), 256, 0, stream>>>(xTs, (const u16*)((char*)wswz + (size_t)(2 * r + 1) * 229376),
        rn_g2 + r * HCH, rn_b2 + r * HCH, rn_be2 + r * HCH, X, X);
  }
  for (int dl = 0; dl < NLAY; ++dl){
    k_mats<<<128, 256, 0, stream>>>(dssp + (size_t)dl * 6 * HCH * NST, A1c, A2c, rC);
    k_dss1<<<dim3(8, 128), 256, 0, stream>>>(X, A1c, PG);
    k_scan<<<512, 256, 0, stream>>>(PG, rC, Sf, Sb);
    k_dss2<<<dim3(8, 128), 256, 0, stream>>>(X, A2c, Sf, Sb, Dv + dl * HCH, PG);
    k_glu2<<<dim3(128, 16), 256, 0, stream>>>(PG, (const u16*)((char*)wglu + (size_t)dl * 131072),
        out_b + dl * 256, ln_g + dl * HCH, ln_b + dl * HCH, X);
  }
  k_xpad<<<16, 256, 0, stream>>>(xTs);
  k_xform<<<dim3(128, 16), 256, 0, stream>>>(X, xTs);
  k_dec2<<<dim3(64, 16), 256, 0, stream>>>(xTs, wdec, dec_b, (float*)d_out);
}

// Round 5
// 1471.985 us; speedup vs baseline: 2.2986x; 1.1846x over previous
//
#include <hip/hip_runtime.h>
#include <hip/hip_bf16.h>

// DSSResNet on MI355X.
//  enc(fp32) -> 3x { conv(MFMA bf16, fused transpose-out) x2 } -> 4x { chunked-SSM DSS (compensated bf16 MFMA) -> MFMA GLU+LN } -> dec(MFMA)
// DSS chunking (C=128): y[i] = T@x (intra) + Re(r^{i+1} Sf) + Re(r^{127-i} Sb); S via 64-step chunk scan.
// Precision: A*x = Ah*xh + Ah*xl + Al*xh (hi/lo bf16 compensation); P fp32; S hi/lo bf16.

#define BN   16
#define HCH  128
#define LSEQ 8192
#define NST  32
#define NLAY 4
#define XT_BSTRIDE 2101248ull   // 8208 rows (l=-8..8199) * 256 B per b

typedef __attribute__((ext_vector_type(4))) float f32x4;
typedef __attribute__((ext_vector_type(8))) short short8;
typedef unsigned short u16;
typedef unsigned int   u32;

struct __align__(8) U2 { u32 x, y; };
struct __align__(16) US8 { u16 v[8]; };
struct __align__(8) US4 { u16 v[4]; };

__device__ __forceinline__ u16 f2bf(float f){
  union { float f; u32 u; } v; v.f = f;
  u32 u = v.u;
  return (u16)((u + 0x7fffu + ((u >> 16) & 1u)) >> 16);   // RNE
}
__device__ __forceinline__ float bf2f(u32 lo16){
  union { u32 u; float f; } v; v.u = lo16 << 16; return v.f;
}
__device__ __forceinline__ float geluf(float v){
  return 0.5f * v * (1.0f + erff(v * 0.70710678118654752f));
}

#define GLDS16(g, l) \
  __builtin_amdgcn_global_load_lds((const __attribute__((address_space(1))) u32*)(g), \
                                   (__attribute__((address_space(3))) u32*)(l), 16, 0, 0)

// ---------------- zero xTs halo rows (l=-8..-1, 8192..8199) ----------------
__global__ void k_xpad(u16* xTs){
  int b = blockIdx.x, t = threadIdx.x;
  char* base = (char*)xTs + (size_t)b * XT_BSTRIDE;
  int r = t >> 4;
  int row = (r < 8) ? r : (8192 + r);          // rows 0..7 and 8200..8207
  f32x4 z = {0.f, 0.f, 0.f, 0.f};
  *(f32x4*)(base + (size_t)row * 256 + (size_t)(t & 15) * 16) = z;
}

// ---------------- resnet weights -> bf16, K-major (k*128+ci), chunked+swizzled ----------------
__global__ void k_wxform(const float* __restrict__ w1, const float* __restrict__ w2, u16* __restrict__ wswz){
  int idx = blockIdx.x * 256 + threadIdx.x;
  if (idx >= 6 * 128 * 896) return;
  int conv = idx / (128 * 896);
  int rem  = idx % (128 * 896);
  int co = rem / 896, K = rem % 896;
  int k = K >> 7, ci = K & 127;
  const float* src = (conv & 1) ? w2 : w1;
  int blk = conv >> 1;
  float v = src[(((size_t)blk * 128 + co) * 128 + ci) * 7 + k];
  int chunk = K >> 6, j = K & 63;
  size_t byteoff = (size_t)conv * 229376 + (size_t)chunk * 16384 + (size_t)co * 128
                 + (u32)((j * 2) ^ ((co & 7) << 4));
  *(u16*)((char*)wswz + byteoff) = f2bf(v);
}

// ---------------- decoder weights -> bf16 [16co][1920K] swizzled ----------------
__global__ void k_wdec(const float* __restrict__ dw, u16* __restrict__ wd){
  int idx = blockIdx.x * 256 + threadIdx.x;
  if (idx >= 16 * 1920) return;
  int co = idx / 1920, K = idx % 1920;
  int k = K >> 7, ci = K & 127;
  float v = (co < 5) ? dw[((size_t)co * 128 + ci) * 15 + k] : 0.f;
  size_t byteoff = (size_t)co * 3840 + (u32)((K * 2) ^ ((co & 7) << 4));
  *(u16*)((char*)wd + byteoff) = f2bf(v);
}

// ---------------- GLU weights: out_w -> per-layer hi/lo swizzled slices ----------------
__global__ void k_wglu(const float* __restrict__ ow, u16* __restrict__ wg){
  int idx = blockIdx.x * 256 + threadIdx.x;
  if (idx >= NLAY * 256 * 128) return;
  int layer = idx >> 15;
  int rem = idx & 32767;
  int q = rem >> 7, k = rem & 127;
  int row = (q & 1) ? (128 + (q >> 1)) : (q >> 1);
  float v = ow[((size_t)layer * 256 + row) * 128 + k];
  u16 hb = f2bf(v);
  u16 lb = f2bf(v - bf2f(hb));
  int a_hi = k >> 6, kk = k & 63;
  size_t base = (size_t)layer * 131072 + (size_t)q * 128 + (u32)((kk * 2) ^ ((q & 7) << 4));
  *(u16*)((char*)wg + base + (size_t)a_hi * 32768) = hb;
  *(u16*)((char*)wg + base + (size_t)(2 + a_hi) * 32768) = lb;
}

// ---------------- DSS per-layer params ----------------
__global__ void k_dssprep(const float* __restrict__ lam_re, const float* __restrict__ lam_im,
                          const float* __restrict__ log_dt, const float* __restrict__ W_re,
                          const float* __restrict__ W_im, float* __restrict__ dssp){
  int idx = blockIdx.x * 256 + threadIdx.x;
  if (idx >= NLAY * HCH * NST) return;
  int layer = idx / (HCH * NST);
  int hn = idx % (HCH * NST);
  int h = hn / NST, n = hn % NST;
  float Lre = -expf(lam_re[layer * NST + n]);
  float Lim = lam_im[layer * NST + n];
  float dt  = expf(log_dt[layer * HCH + h]);
  float are = dt * Lre, aim = dt * Lim;
  float er = expf(are);
  float rre = er * cosf(aim);
  float rim = er * sinf(aim);
  float nre = rre - 1.f, nim = rim;
  float den = 1.f / (Lre * Lre + Lim * Lim);
  float fre = (nre * Lre + nim * Lim) * den;
  float fim = (nim * Lre - nre * Lim) * den;
  float* base = dssp + (size_t)layer * 6 * HCH * NST;
  base[(0 * HCH + h) * NST + n] = rre;
  base[(1 * HCH + h) * NST + n] = rim;
  #pragma unroll
  for (int cc = 0; cc < 2; ++cc){
    float wr_ = W_re[(((size_t)layer * 2 + cc) * HCH + h) * NST + n];
    float wi_ = W_im[(((size_t)layer * 2 + cc) * HCH + h) * NST + n];
    base[((2 + 2 * cc) * HCH + h) * NST + n] = wr_ * fre - wi_ * fim;
    base[((3 + 2 * cc) * HCH + h) * NST + n] = wr_ * fim + wi_ * fre;
  }
}

// ---------------- per-layer chunk matrices (hi/lo bf16, swizzled slices) ----------------
__global__ __launch_bounds__(256) void k_mats(const float* __restrict__ pp,
                                              u16* __restrict__ A1c, u16* __restrict__ A2c,
                                              float* __restrict__ rC){
  int h = blockIdx.x, t = threadIdx.x;
  __shared__ float pre[129][33], pim[129][33];
  __shared__ float w0re[32], w0im[32], w1re[32], w1im[32];
  __shared__ float tf[128], tb[128];
  if (t < 32){
    int n = t;
    float rre = pp[(0 * HCH + h) * NST + n], rim = pp[(1 * HCH + h) * NST + n];
    w0re[n] = pp[(2 * HCH + h) * NST + n]; w0im[n] = pp[(3 * HCH + h) * NST + n];
    w1re[n] = pp[(4 * HCH + h) * NST + n]; w1im[n] = pp[(5 * HCH + h) * NST + n];
    float pr = 1.f, pi = 0.f;
    pre[0][n] = 1.f; pim[0][n] = 0.f;
    for (int p = 1; p <= 128; ++p){
      float nr = pr * rre - pi * rim;
      float ni = pr * rim + pi * rre;
      pr = nr; pi = ni;
      pre[p][n] = pr; pim[p][n] = pi;
    }
    rC[h * 64 + 2 * n] = pr; rC[h * 64 + 2 * n + 1] = pi;
  }
  __syncthreads();
  if (t < 128){
    float s = 0.f;
    for (int n = 0; n < 32; ++n) s += w0re[n] * pre[t][n] - w0im[n] * pim[t][n];
    tf[t] = s;
  } else {
    int d = t - 128;
    if (d == 0) tb[0] = 0.f;
    else {
      float s = 0.f;
      for (int n = 0; n < 32; ++n) s += w1re[n] * pre[d - 1][n] - w1im[n] * pim[d - 1][n];
      tb[d] = s;
    }
  }
  __syncthreads();
  for (int idx = t; idx < 4 * 128 * 64; idx += 256){
    int a = idx >> 13, rem = idx & 8191, q = rem >> 6, k = rem & 63;
    int j = (a & 1) * 64 + k;
    int n, p; float wr_, wi_;
    if (q < 64){ n = q >> 1; p = 127 - j; wr_ = w0re[n]; wi_ = w0im[n]; }
    else       { n = (q - 64) >> 1; p = j; wr_ = w1re[n]; wi_ = w1im[n]; }
    float pr = pre[p][n], pi = pim[p][n];
    float v = (q & 1) ? (wr_ * pi + wi_ * pr) : (wr_ * pr - wi_ * pi);
    u16 hb = f2bf(v);
    u16 ob = (a < 2) ? hb : f2bf(v - bf2f(hb));
    *(u16*)((char*)A1c + (size_t)h * 65536 + (size_t)a * 16384 + (size_t)q * 128
            + (u32)((k * 2) ^ ((q & 7) << 4))) = ob;
  }
  for (int idx = t; idx < 8 * 128 * 64; idx += 256){
    int a = idx >> 13, rem = idx & 8191, i = rem >> 6, k = rem & 63;
    float v; bool lo;
    if (a < 4){
      int colT = (a & 1) * 64 + k;
      v = (i >= colT) ? tf[i - colT] : tb[colT - i];
      lo = (a >= 2);
    } else {
      int n = k >> 1;
      int p = (a < 6) ? (i + 1) : (127 - i);
      v = (k & 1) ? -pim[p][n] : pre[p][n];
      lo = (a == 5) || (a == 7);
    }
    u16 hb = f2bf(v);
    u16 ob = lo ? f2bf(v - bf2f(hb)) : hb;
    *(u16*)((char*)A2c + (size_t)h * 131072 + (size_t)a * 16384 + (size_t)i * 128
            + (u32)((k * 2) ^ ((i & 7) << 4))) = ob;
  }
}

// ---------------- encoder conv: (B,5,L) -> (B,128,L), K=15 'same', fp32 ----------------
__global__ __launch_bounds__(128) void k_enc(const float* __restrict__ xin, const float* __restrict__ w,
                                             const float* __restrict__ bias, float* __restrict__ X){
  int b = blockIdx.y, l0 = blockIdx.x * 64;
  int t = threadIdx.x;                       // t = co
  __shared__ float xs[5][78];
  for (int i = t; i < 5 * 78; i += 128){
    int ci = i / 78, j = i % 78;
    int l = l0 - 7 + j;
    xs[ci][j] = (l >= 0 && l < LSEQ) ? xin[((size_t)b * 5 + ci) * LSEQ + l] : 0.f;
  }
  float wreg[75];
  #pragma unroll
  for (int i = 0; i < 75; ++i) wreg[i] = w[t * 75 + i];
  float bc = bias[t];
  __syncthreads();
  size_t orow = ((size_t)b * HCH + t) * LSEQ + l0;
  for (int gb = 0; gb < 8; ++gb){
    float acc[8] = {0, 0, 0, 0, 0, 0, 0, 0};
    #pragma unroll
    for (int ci = 0; ci < 5; ++ci){
      #pragma unroll
      for (int k = 0; k < 15; ++k){
        float wv = wreg[ci * 15 + k];
        #pragma unroll
        for (int j = 0; j < 8; ++j)
          acc[j] = fmaf(wv, xs[ci][gb * 8 + j + k], acc[j]);
      }
    }
    f32x4 o0 = {acc[0] + bc, acc[1] + bc, acc[2] + bc, acc[3] + bc};
    f32x4 o1 = {acc[4] + bc, acc[5] + bc, acc[6] + bc, acc[7] + bc};
    *(f32x4*)&X[orow + gb * 8]     = o0;
    *(f32x4*)&X[orow + gb * 8 + 4] = o1;
  }
}

// ---------------- X (b,h,l) fp32 -> xTs (b,l,ci) bf16, row-swizzled by (l&7) ----------------
__global__ __launch_bounds__(256) void k_xform(const float* __restrict__ Xin, u16* __restrict__ xTs){
  int b = blockIdx.y, l0 = blockIdx.x * 64;
  int t = threadIdx.x;
  __shared__ float tile[128][65];
  #pragma unroll
  for (int it = 0; it < 32; ++it){
    int idx = t + it * 256;
    int ci = idx >> 6, j = idx & 63;
    tile[ci][j] = Xin[((size_t)b * HCH + ci) * LSEQ + l0 + j];
  }
  __syncthreads();
  int rl = t >> 2, q = t & 3;
  int l = l0 + rl;
  char* rowp = (char*)xTs + (size_t)b * XT_BSTRIDE + (size_t)(l + 8) * 256;
  u32 key = ((u32)l & 7u) << 4;
  #pragma unroll
  for (int ii = 0; ii < 8; ++ii){
    int c0 = q * 32 + ii * 4;
    U2 val;
    val.x = (u32)f2bf(tile[c0 + 0][rl]) | ((u32)f2bf(tile[c0 + 1][rl]) << 16);
    val.y = (u32)f2bf(tile[c0 + 2][rl]) | ((u32)f2bf(tile[c0 + 3][rl]) << 16);
    *(U2*)(rowp + (((u32)(c0 * 2)) ^ key)) = val;
  }
}

// ---------------- resnet conv (K=7) as MFMA GEMM, fused bf16 transpose-out ----------------
__global__ __launch_bounds__(256, 2) void k_conv(
    const u16* __restrict__ xTs, const u16* __restrict__ wcv,
    const float* __restrict__ bng, const float* __restrict__ bnb, const float* __restrict__ bnbe,
    const float* __restrict__ Xres, float* __restrict__ Xout, u16* __restrict__ xTsOut)
{
  int b = blockIdx.y, l0 = blockIdx.x * 128;
  int tid = threadIdx.x, lane = tid & 63, wv = tid >> 6;
  int wr = wv >> 1, wc = wv & 1;
  int lan15 = lane & 15, lhi = lane >> 4;

  __shared__ alignas(16) u16 xt[144 * 128];
  __shared__ alignas(16) u16 wch[2][128 * 64];

  const char* xsrc = (const char*)xTs + (size_t)b * XT_BSTRIDE + (size_t)l0 * 256;
  #pragma unroll
  for (int is = 0; is < 9; ++is){
    int off = is * 4096 + wv * 1024;
    GLDS16(xsrc + off + (lane << 4), (char*)xt + off);
  }
  {
    const char* wsrc = (const char*)wcv;
    #pragma unroll
    for (int is = 0; is < 4; ++is){
      int off = is * 4096 + wv * 1024;
      GLDS16(wsrc + off + (lane << 4), (char*)&wch[0][0] + off);
    }
  }
  asm volatile("s_waitcnt vmcnt(0)" ::: "memory");
  __syncthreads();

  f32x4 acc[4][4];
  #pragma unroll
  for (int i = 0; i < 4; ++i)
    #pragma unroll
    for (int j = 0; j < 4; ++j) acc[i][j] = (f32x4){0.f, 0.f, 0.f, 0.f};

  for (int c = 0; c < 14; ++c){
    int cur = c & 1;
    if (c < 13){
      const char* wsrc = (const char*)wcv + (size_t)(c + 1) * 16384;
      #pragma unroll
      for (int is = 0; is < 4; ++is){
        int off = is * 4096 + wv * 1024;
        GLDS16(wsrc + off + (lane << 4), (char*)&wch[cur ^ 1][0] + off);
      }
    }
    int k = c >> 1;
    const char* wb = (const char*)&wch[cur][0];
    #pragma unroll
    for (int ks = 0; ks < 2; ++ks){
      short8 af[4], bf[4];
      int j0 = ks * 32 + lhi * 8;
      #pragma unroll
      for (int mt = 0; mt < 4; ++mt){
        int co = wr * 64 + mt * 16 + lan15;
        af[mt] = *(const short8*)(wb + co * 128 + ((j0 * 2) ^ ((co & 7) << 4)));
      }
      int ci0 = (c & 1) * 64 + ks * 32 + lhi * 8;
      #pragma unroll
      for (int nt = 0; nt < 4; ++nt){
        int ll = wc * 64 + nt * 16 + lan15;
        int row = ll + k + 5;                  // staged row of source l = l0+ll+k-3 (halo 8)
        int lg = l0 + ll + k - 3;
        bf[nt] = *(const short8*)((const char*)xt + row * 256 + ((ci0 * 2) ^ ((lg & 7) << 4)));
      }
      #pragma unroll
      for (int mt = 0; mt < 4; ++mt)
        #pragma unroll
        for (int nt = 0; nt < 4; ++nt)
          acc[mt][nt] = __builtin_amdgcn_mfma_f32_16x16x32_bf16(af[mt], bf[nt], acc[mt][nt], 0, 0, 0);
    }
    asm volatile("s_waitcnt vmcnt(0)" ::: "memory");
    __syncthreads();
  }

  bool hasres = (Xres != nullptr);
  bool hasout = (Xout != nullptr);
  u16* tr = xt;   // reuse as 128l x 256B transpose buffer (32 KB)
  #pragma unroll
  for (int mt = 0; mt < 4; ++mt){
    float A4[4], B4[4];
    int co0 = wr * 64 + mt * 16 + (lhi << 2);
    #pragma unroll
    for (int reg = 0; reg < 4; ++reg){
      A4[reg] = bng[co0 + reg] * 0.99999500003749968f;
      B4[reg] = fmaf(bnb[co0 + reg], A4[reg], bnbe[co0 + reg]);
    }
    #pragma unroll
    for (int nt = 0; nt < 4; ++nt){
      int ll = wc * 64 + nt * 16 + lan15;
      int l = l0 + ll;
      US4 o;
      #pragma unroll
      for (int reg = 0; reg < 4; ++reg){
        float v = fmaf(acc[mt][nt][reg], A4[reg], B4[reg]);
        if (hasres) v += Xres[((size_t)b * HCH + co0 + reg) * LSEQ + l];
        v = fmaxf(v, 0.f);
        if (hasout) Xout[((size_t)b * HCH + co0 + reg) * LSEQ + l] = v;
        o.v[reg] = f2bf(v);
      }
      *(US4*)((char*)tr + ll * 256 + (u32)((co0 * 2) ^ ((ll & 7) << 4))) = o;
    }
  }
  if (xTsOut){
    __syncthreads();
    int row = tid >> 1, half = tid & 1;
    const char* s = (const char*)tr + row * 256 + half * 128;
    char* d = (char*)xTsOut + (size_t)b * XT_BSTRIDE + (size_t)(l0 + row + 8) * 256 + half * 128;
    #pragma unroll
    for (int i = 0; i < 8; ++i)
      *(f32x4*)(d + i * 16) = *(const f32x4*)(s + i * 16);
  }
}

// ---------------- stage x tile (hi/lo bf16) into LDS: [128 col][128 k], col=(c&7)*16+b ----------------
__device__ __forceinline__ void stage_x_tile(const float* __restrict__ X, int h, int ct,
                                             char* xh, char* xl, int t){
  int k8 = t & 15;            // k-group: k = k8*8
  int c0 = t >> 4;            // base col
  #pragma unroll
  for (int it = 0; it < 8; ++it){
    int col = c0 + it * 16;
    int c = ct * 8 + (col >> 4), b = col & 15;
    const float* src = X + ((size_t)b * HCH + h) * LSEQ + (size_t)c * 128 + k8 * 8;
    f32x4 v0 = *(const f32x4*)src;
    f32x4 v1 = *(const f32x4*)(src + 4);
    US8 hi, lo;
    #pragma unroll
    for (int e = 0; e < 4; ++e){
      u16 hb = f2bf(v0[e]);
      hi.v[e] = hb; lo.v[e] = f2bf(v0[e] - bf2f(hb));
      u16 hb2 = f2bf(v1[e]);
      hi.v[e + 4] = hb2; lo.v[e + 4] = f2bf(v1[e] - bf2f(hb2));
    }
    u32 off = (u32)col * 256 + (u32)((k8 * 16) ^ ((col & 7) << 4));
    *(US8*)(xh + off) = hi;
    *(US8*)(xl + off) = lo;
  }
}

// ---------------- GEMM1: P[128q][col] = A1h@xh + A1h@xl + A1l@xh (per h,ct) ----------------
// 80 KB LDS -> 2 blocks/CU; A-slice-major pass order (each of 4 slices loaded once)
__global__ __launch_bounds__(256) void k_dss1(const float* __restrict__ X,
                                              const u16* __restrict__ A1c,
                                              float* __restrict__ P){
  int h = blockIdx.x, ct = blockIdx.y;
  int tid = threadIdx.x, lane = tid & 63, wv = tid >> 6;
  int wr = wv >> 1, wc = wv & 1, lan15 = lane & 15, lhi = lane >> 4;
  __shared__ alignas(16) u16 bx[32768];      // xh [0,32KB) xl [32KB,64KB)
  __shared__ alignas(16) u16 ach[8192];      // 16 KB single-buffered A slice

  stage_x_tile(X, h, ct, (char*)bx, (char*)bx + 32768, tid);
  const char* abase = (const char*)A1c + (size_t)h * 65536;

  f32x4 acc[4][4];
  #pragma unroll
  for (int i = 0; i < 4; ++i)
    #pragma unroll
    for (int j = 0; j < 4; ++j) acc[i][j] = (f32x4){0.f, 0.f, 0.f, 0.f};

  #pragma unroll
  for (int g = 0; g < 4; ++g){               // slices: 0=Ah(k0) 1=Ah(k64) 2=Al(k0) 3=Al(k64)
    __syncthreads();
    const char* an = abase + (size_t)g * 16384;
    #pragma unroll
    for (int is = 0; is < 4; ++is){
      int off = is * 4096 + wv * 1024;
      GLDS16(an + off + (lane << 4), (char*)ach + off);
    }
    asm volatile("s_waitcnt vmcnt(0)" ::: "memory");
    __syncthreads();
    int kb0 = (g & 1) * 64;
    int npass = (g < 2) ? 2 : 1;             // hi-A pairs with xh then xl; lo-A with xh only
    for (int p = 0; p < npass; ++p){
      const char* bt = (const char*)bx + p * 32768;
      #pragma unroll
      for (int ks = 0; ks < 2; ++ks){
        int ka = ks * 32 + lhi * 8;
        short8 af[4], bf[4];
        #pragma unroll
        for (int mt = 0; mt < 4; ++mt){
          int q = wr * 64 + mt * 16 + lan15;
          af[mt] = *(const short8*)((const char*)ach + q * 128 + ((ka * 2) ^ ((q & 7) << 4)));
        }
        int kb = kb0 + ka;
        #pragma unroll
        for (int nt = 0; nt < 4; ++nt){
          int col = wc * 64 + nt * 16 + lan15;
          bf[nt] = *(const short8*)(bt + col * 256 + ((kb * 2) ^ ((col & 7) << 4)));
        }
        #pragma unroll
        for (int mt = 0; mt < 4; ++mt)
          #pragma unroll
          for (int nt = 0; nt < 4; ++nt)
            acc[mt][nt] = __builtin_amdgcn_mfma_f32_16x16x32_bf16(af[mt], bf[nt], acc[mt][nt], 0, 0, 0);
      }
    }
  }

  #pragma unroll
  for (int mt = 0; mt < 4; ++mt)
    #pragma unroll
    for (int nt = 0; nt < 4; ++nt){
      int col = ct * 128 + wc * 64 + nt * 16 + lan15;
      int q0 = wr * 64 + mt * 16 + (lhi << 2);
      *(f32x4*)&P[((size_t)h * 1024 + col) * 128 + q0] = acc[mt][nt];
    }
}

// ---------------- chunk scan (fp32): S[c] written (hi/lo bf16, swizzled) before update ----------------
__global__ __launch_bounds__(256) void k_scan(const float* __restrict__ P,
                                              const float* __restrict__ rC,
                                              u16* __restrict__ Sf, u16* __restrict__ Sb){
  int part = blockIdx.x & 3, h = blockIdx.x >> 2;
  int t = threadIdx.x;
  int dir = part >> 1;
  int b = (part & 1) * 8 + (t >> 5);
  int n = t & 31;
  float rre = rC[h * 64 + 2 * n], rim = rC[h * 64 + 2 * n + 1];
  u16* SO = dir ? Sb : Sf;
  const float* pbase = P + (size_t)h * 131072 + (size_t)b * 128 + dir * 64 + 2 * n;
  float sre = 0.f, sim = 0.f;
  u32 key = ((u32)b & 7u) << 4;
  for (int ii = 0; ii < 64; ++ii){
    int c = dir ? (63 - ii) : ii;
    u16 hr = f2bf(sre), hm = f2bf(sim);
    u32 hw = (u32)hr | ((u32)hm << 16);
    u32 lw = (u32)f2bf(sre - bf2f(hr)) | ((u32)f2bf(sim - bf2f(hm)) << 16);
    char* sp = (char*)SO + ((size_t)(h * 8 + (c >> 3)) * 2) * 16384
             + (size_t)((c & 7) * 16 + b) * 128 + (u32)((4 * n) ^ key);
    *(u32*)sp = hw;
    *(u32*)(sp + 16384) = lw;
    const float* pp = pbase + (size_t)c * 2048;
    float pr = pp[0], pi = pp[1];
    float nr = rre * sre - rim * sim + pr;
    float ni = rre * sim + rim * sre + pi;
    sre = nr; sim = ni;
  }
}

// ---------------- GEMM2: Y = Vf@Sf + Vb@Sb (first) + T@x (second); G = gelu(Y + D*x) ----------------
// 80 KB LDS -> 2 blocks/CU; x staged last so epilogue reads x from LDS (no X re-read)
__global__ __launch_bounds__(256) void k_dss2(const float* __restrict__ X,
                                              const u16* __restrict__ A2c,
                                              const u16* __restrict__ Sf,
                                              const u16* __restrict__ Sb,
                                              const float* __restrict__ Dv,
                                              float* __restrict__ G){
  int h = blockIdx.x, ct = blockIdx.y;
  int tid = threadIdx.x, lane = tid & 63, wv = tid >> 6;
  int wr = wv >> 1, wc = wv & 1, lan15 = lane & 15, lhi = lane >> 4;
  __shared__ alignas(16) u16 bx[32768];      // V: Sfh|Sfl|Sbh|Sbl (4x16KB); T: xh|xl
  __shared__ alignas(16) u16 ach[8192];

  // ---- stage S tiles ----
  {
    const char* st0 = (const char*)Sf + ((size_t)(h * 8 + ct) * 2) * 16384;
    const char* st2 = (const char*)Sb + ((size_t)(h * 8 + ct) * 2) * 16384;
    const char* stile[4] = {st0, st0 + 16384, st2, st2 + 16384};
    #pragma unroll
    for (int tt = 0; tt < 4; ++tt){
      #pragma unroll
      for (int is = 0; is < 4; ++is){
        int off = is * 4096 + wv * 1024;
        GLDS16(stile[tt] + off + (lane << 4), (char*)bx + tt * 16384 + off);
      }
    }
  }
  const char* abase = (const char*)A2c + (size_t)h * 131072;

  f32x4 acc[4][4];
  #pragma unroll
  for (int i = 0; i < 4; ++i)
    #pragma unroll
    for (int j = 0; j < 4; ++j) acc[i][j] = (f32x4){0.f, 0.f, 0.f, 0.f};

  // ---- phase V: slices 4=Vfh{Sfh,Sfl} 5=Vfl{Sfh} 6=Vbh{Sbh,Sbl} 7=Vbl{Sbh}; K=64 ----
  {
    const int bo0[4] = {0, 0, 32768, 32768};
    #pragma unroll
    for (int g = 0; g < 4; ++g){
      __syncthreads();
      const char* an = abase + (size_t)(4 + g) * 16384;
      #pragma unroll
      for (int is = 0; is < 4; ++is){
        int off = is * 4096 + wv * 1024;
        GLDS16(an + off + (lane << 4), (char*)ach + off);
      }
      asm volatile("s_waitcnt vmcnt(0)" ::: "memory");
      __syncthreads();
      int npass = (g & 1) ? 1 : 2;
      for (int p = 0; p < npass; ++p){
        const char* bt = (const char*)bx + bo0[g] + p * 16384;
        #pragma unroll
        for (int ks = 0; ks < 2; ++ks){
          int ka = ks * 32 + lhi * 8;
          short8 af[4], bf[4];
          #pragma unroll
          for (int mt = 0; mt < 4; ++mt){
            int i = wr * 64 + mt * 16 + lan15;
            af[mt] = *(const short8*)((const char*)ach + i * 128 + ((ka * 2) ^ ((i & 7) << 4)));
          }
          #pragma unroll
          for (int nt = 0; nt < 4; ++nt){
            int col = wc * 64 + nt * 16 + lan15;
            bf[nt] = *(const short8*)(bt + col * 128 + ((ka * 2) ^ ((col & 7) << 4)));
          }
          #pragma unroll
          for (int mt = 0; mt < 4; ++mt)
            #pragma unroll
            for (int nt = 0; nt < 4; ++nt)
              acc[mt][nt] = __builtin_amdgcn_mfma_f32_16x16x32_bf16(af[mt], bf[nt], acc[mt][nt], 0, 0, 0);
        }
      }
    }
  }
  // ---- restage: x hi/lo over the S tiles ----
  __syncthreads();
  stage_x_tile(X, h, ct, (char*)bx, (char*)bx + 32768, tid);
  // ---- phase T: slices 0=Th(k0){xh,xl} 1=Th(k64){xh,xl} 2=Tl(k0){xh} 3=Tl(k64){xh} ----
  #pragma unroll
  for (int g = 0; g < 4; ++g){
    __syncthreads();
    const char* an = abase + (size_t)g * 16384;
    #pragma unroll
    for (int is = 0; is < 4; ++is){
      int off = is * 4096 + wv * 1024;
      GLDS16(an + off + (lane << 4), (char*)ach + off);
    }
    asm volatile("s_waitcnt vmcnt(0)" ::: "memory");
    __syncthreads();
    int kb0 = (g & 1) * 64;
    int npass = (g < 2) ? 2 : 1;
    for (int p = 0; p < npass; ++p){
      const char* bt = (const char*)bx + p * 32768;
      #pragma unroll
      for (int ks = 0; ks < 2; ++ks){
        int ka = ks * 32 + lhi * 8;
        short8 af[4], bf[4];
        #pragma unroll
        for (int mt = 0; mt < 4; ++mt){
          int i = wr * 64 + mt * 16 + lan15;
          af[mt] = *(const short8*)((const char*)ach + i * 128 + ((ka * 2) ^ ((i & 7) << 4)));
        }
        int kb = kb0 + ka;
        #pragma unroll
        for (int nt = 0; nt < 4; ++nt){
          int col = wc * 64 + nt * 16 + lan15;
          bf[nt] = *(const short8*)(bt + col * 256 + ((kb * 2) ^ ((col & 7) << 4)));
        }
        #pragma unroll
        for (int mt = 0; mt < 4; ++mt)
          #pragma unroll
          for (int nt = 0; nt < 4; ++nt)
            acc[mt][nt] = __builtin_amdgcn_mfma_f32_16x16x32_bf16(af[mt], bf[nt], acc[mt][nt], 0, 0, 0);
      }
    }
  }
  // ---- epilogue: G = gelu(Y + D*x), x reconstructed from LDS hi/lo ----
  float Dh = Dv[h];
  #pragma unroll
  for (int mt = 0; mt < 4; ++mt)
    #pragma unroll
    for (int nt = 0; nt < 4; ++nt){
      int col = wc * 64 + nt * 16 + lan15;
      int c = ct * 8 + (col >> 4), b = col & 15;
      int i0 = wr * 64 + mt * 16 + (lhi << 2);
      u32 off = (u32)col * 256 + (u32)((2 * i0) ^ ((col & 7) << 4));
      US4 hx = *(const US4*)((const char*)bx + off);
      US4 lx = *(const US4*)((const char*)bx + 32768 + off);
      size_t base = ((size_t)b * HCH + h) * LSEQ + (size_t)c * 128 + i0;
      f32x4 ov;
      #pragma unroll
      for (int e = 0; e < 4; ++e){
        float xv = bf2f(hx.v[e]) + bf2f(lx.v[e]);
        ov[e] = geluf(acc[mt][nt][e] + Dh * xv);
      }
      *(f32x4*)&G[base] = ov;
    }
}

// ---------------- MFMA GLU+LN: y = Wg @ G (compensated); z=a*sig(g); u=z+X; LN -> X ----------------
__global__ __launch_bounds__(256) void k_glu2(
    const float* __restrict__ G,
    const u16* __restrict__ Wg,      // layer slices: [256 q][64 k] x {hi0,hi1,lo0,lo1}
    const float* __restrict__ ob,
    const float* __restrict__ lng, const float* __restrict__ lnb,
    float* __restrict__ X)
{
  int b = blockIdx.y, l0 = blockIdx.x * 64;
  int tid = threadIdx.x, lane = tid & 63, wv = tid >> 6;
  int lan15 = lane & 15, lhi = lane >> 4;
  __shared__ alignas(16) u16 gt[2][64 * 128];   // hi/lo : [col l][128 h], swizzled by (l&7)<<4
  __shared__ alignas(16) u16 ach[256 * 64];     // A slice 32 KB
  __shared__ float lnbuf[4][64][2];

  // ---- stage G transposed, hi/lo split ----
  {
    int hp = tid & 63, lgrp = tid >> 6;
    const float* g0 = G + ((size_t)b * HCH + 2 * hp) * LSEQ + l0 + lgrp * 16;
    const float* g1 = g0 + LSEQ;
    #pragma unroll
    for (int j4 = 0; j4 < 4; ++j4){
      f32x4 r0 = *(const f32x4*)(g0 + j4 * 4);
      f32x4 r1 = *(const f32x4*)(g1 + j4 * 4);
      #pragma unroll
      for (int e = 0; e < 4; ++e){
        int l = lgrp * 16 + j4 * 4 + e;
        u16 h0 = f2bf(r0[e]), h1 = f2bf(r1[e]);
        u16 q0 = f2bf(r0[e] - bf2f(h0)), q1 = f2bf(r1[e] - bf2f(h1));
        u32 off = (u32)l * 256 + (((u32)hp * 4) ^ (((u32)l & 7u) << 4));
        *(u32*)((char*)&gt[0][0] + off) = (u32)h0 | ((u32)h1 << 16);
        *(u32*)((char*)&gt[1][0] + off) = (u32)q0 | ((u32)q1 << 16);
      }
    }
  }

  f32x4 acc[4][4];
  #pragma unroll
  for (int i = 0; i < 4; ++i)
    #pragma unroll
    for (int j = 0; j < 4; ++j) acc[i][j] = (f32x4){0.f, 0.f, 0.f, 0.f};

  const int asel[6] = {0, 1, 0, 1, 2, 3};
  const int bsel[6] = {0, 0, 1, 1, 0, 0};
  const int bk0 [6] = {0, 64, 0, 64, 0, 64};
  for (int s = 0; s < 6; ++s){
    __syncthreads();
    const char* an = (const char*)Wg + (size_t)asel[s] * 32768;
    #pragma unroll
    for (int is = 0; is < 8; ++is){
      int off = is * 4096 + wv * 1024;
      GLDS16(an + off + (lane << 4), (char*)ach + off);
    }
    asm volatile("s_waitcnt vmcnt(0)" ::: "memory");
    __syncthreads();
    const char* bt = (const char*)&gt[bsel[s]][0];
    #pragma unroll
    for (int ks = 0; ks < 2; ++ks){
      int ka = ks * 32 + lhi * 8;
      short8 af[4], bf[4];
      #pragma unroll
      for (int mt = 0; mt < 4; ++mt){
        int q = wv * 64 + mt * 16 + lan15;
        af[mt] = *(const short8*)((const char*)ach + q * 128 + ((ka * 2) ^ ((q & 7) << 4)));
      }
      int kb = bk0[s] + ka;
      #pragma unroll
      for (int nt = 0; nt < 4; ++nt){
        int col = nt * 16 + lan15;
        bf[nt] = *(const short8*)(bt + col * 256 + ((kb * 2) ^ ((col & 7) << 4)));
      }
      #pragma unroll
      for (int mt = 0; mt < 4; ++mt)
        #pragma unroll
        for (int nt = 0; nt < 4; ++nt)
          acc[mt][nt] = __builtin_amdgcn_mfma_f32_16x16x32_bf16(af[mt], bf[nt], acc[mt][nt], 0, 0, 0);
    }
  }

  // ---- GLU + skip; partial LN sums ----
  float s1v[4] = {0, 0, 0, 0}, s2v[4] = {0, 0, 0, 0};
  float oba[4][2], obg[4][2];
  #pragma unroll
  for (int mt = 0; mt < 4; ++mt)
    #pragma unroll
    for (int e = 0; e < 2; ++e){
      int o = wv * 32 + mt * 8 + lhi * 2 + e;
      oba[mt][e] = ob[o]; obg[mt][e] = ob[o + 128];
    }
  #pragma unroll
  for (int nt = 0; nt < 4; ++nt){
    int l = l0 + nt * 16 + lan15;
    #pragma unroll
    for (int mt = 0; mt < 4; ++mt){
      #pragma unroll
      for (int e = 0; e < 2; ++e){
        int o = wv * 32 + mt * 8 + lhi * 2 + e;
        float a = acc[mt][nt][2 * e]     + oba[mt][e];
        float g = acc[mt][nt][2 * e + 1] + obg[mt][e];
        float z = a * (1.f / (1.f + expf(-g)));
        float u = z + X[((size_t)b * HCH + o) * LSEQ + l];
        acc[mt][nt][2 * e] = u;
        s1v[nt] += u; s2v[nt] += u * u;
      }
    }
  }
  #pragma unroll
  for (int nt = 0; nt < 4; ++nt){
    s1v[nt] += __shfl_xor(s1v[nt], 16, 64);
    s1v[nt] += __shfl_xor(s1v[nt], 32, 64);
    s2v[nt] += __shfl_xor(s2v[nt], 16, 64);
    s2v[nt] += __shfl_xor(s2v[nt], 32, 64);
  }
  if (lhi == 0){
    #pragma unroll
    for (int nt = 0; nt < 4; ++nt){
      lnbuf[wv][nt * 16 + lan15][0] = s1v[nt];
      lnbuf[wv][nt * 16 + lan15][1] = s2v[nt];
    }
  }
  __syncthreads();
  #pragma unroll
  for (int nt = 0; nt < 4; ++nt){
    int col = nt * 16 + lan15;
    float S1 = lnbuf[0][col][0] + lnbuf[1][col][0] + lnbuf[2][col][0] + lnbuf[3][col][0];
    float S2 = lnbuf[0][col][1] + lnbuf[1][col][1] + lnbuf[2][col][1] + lnbuf[3][col][1];
    float mu = S1 * (1.f / 128.f);
    float var = S2 * (1.f / 128.f) - mu * mu;
    float rs = rsqrtf(var + 1e-5f);
    int l = l0 + col;
    #pragma unroll
    for (int mt = 0; mt < 4; ++mt)
      #pragma unroll
      for (int e = 0; e < 2; ++e){
        int o = wv * 32 + mt * 8 + lhi * 2 + e;
        float u = acc[mt][nt][2 * e];
        X[((size_t)b * HCH + o) * LSEQ + l] = (u - mu) * rs * lng[o] + lnb[o];
      }
  }
}

// ---------------- decoder as MFMA: M=16(5 used), K=1920, N=128 l-tile ----------------
__global__ __launch_bounds__(256, 1) void k_dec2(const u16* __restrict__ xTs, const u16* __restrict__ wd,
                                                 const float* __restrict__ bias, float* __restrict__ out){
  int b = blockIdx.y, l0 = blockIdx.x * 128;
  int tid = threadIdx.x, lane = tid & 63, wv = tid >> 6;
  int lan15 = lane & 15, lhi = lane >> 4;
  __shared__ alignas(16) u16 xt[144 * 128];
  __shared__ alignas(16) u16 ws[16 * 1920];
  const char* xsrc = (const char*)xTs + (size_t)b * XT_BSTRIDE + (size_t)l0 * 256;
  #pragma unroll
  for (int is = 0; is < 9; ++is){
    int off = is * 4096 + wv * 1024;
    GLDS16(xsrc + off + (lane << 4), (char*)xt + off);
  }
  #pragma unroll
  for (int is = 0; is < 15; ++is){
    int off = is * 4096 + wv * 1024;
    GLDS16((const char*)wd + off + (lane << 4), (char*)ws + off);
  }
  asm volatile("s_waitcnt vmcnt(0)" ::: "memory");
  __syncthreads();
  f32x4 acc[2] = {(f32x4){0, 0, 0, 0}, (f32x4){0, 0, 0, 0}};
  for (int k = 0; k < 15; ++k){
    #pragma unroll
    for (int ks = 0; ks < 4; ++ks){
      int K = k * 128 + ks * 32 + lhi * 8;
      short8 af = *(const short8*)((const char*)ws + lan15 * 3840 + (((u32)(K * 2)) ^ (((u32)lan15 & 7u) << 4)));
      #pragma unroll
      for (int nt = 0; nt < 2; ++nt){
        int ll = wv * 32 + nt * 16 + lan15;
        int lg = l0 + ll + k - 7;
        int row = ll + k + 1;
        short8 bf = *(const short8*)((const char*)xt + row * 256 + ((((ks * 32 + lhi * 8) * 2)) ^ ((lg & 7) << 4)));
        acc[nt] = __builtin_amdgcn_mfma_f32_16x16x32_bf16(af, bf, acc[nt], 0, 0, 0);
      }
    }
  }
  #pragma unroll
  for (int nt = 0; nt < 2; ++nt){
    int l = l0 + wv * 32 + nt * 16 + lan15;
    #pragma unroll
    for (int reg = 0; reg < 4; ++reg){
      int co = (lhi << 2) + reg;
      if (co < 5) out[((size_t)b * 5 + co) * LSEQ + l] = acc[nt][reg] + bias[co];
    }
  }
}

extern "C" void kernel_launch(void* const* d_in, const int* in_sizes, int n_in,
                              void* d_out, int out_size, void* d_ws, size_t ws_size,
                              hipStream_t stream){
  (void)in_sizes; (void)n_in; (void)out_size; (void)ws_size;
  const float* x_in   = (const float*)d_in[0];
  const float* enc_w  = (const float*)d_in[1];
  const float* enc_b  = (const float*)d_in[2];
  const float* rn_w1  = (const float*)d_in[3];
  const float* rn_b1  = (const float*)d_in[4];
  const float* rn_g1  = (const float*)d_in[5];
  const float* rn_be1 = (const float*)d_in[6];
  const float* rn_w2  = (const float*)d_in[7];
  const float* rn_b2  = (const float*)d_in[8];
  const float* rn_g2  = (const float*)d_in[9];
  const float* rn_be2 = (const float*)d_in[10];
  const float* lam_re = (const float*)d_in[11];
  const float* lam_im = (const float*)d_in[12];
  const float* log_dt = (const float*)d_in[13];
  const float* W_re   = (const float*)d_in[14];
  const float* W_im   = (const float*)d_in[15];
  const float* Dv     = (const float*)d_in[16];
  const float* out_w  = (const float*)d_in[17];
  const float* out_b  = (const float*)d_in[18];
  const float* ln_g   = (const float*)d_in[19];
  const float* ln_b   = (const float*)d_in[20];
  const float* dec_w  = (const float*)d_in[21];
  const float* dec_b  = (const float*)d_in[22];

  char* ws = (char*)d_ws;
  float* X    = (float*)(ws + 0ull);              // 64 MB residual stream
  float* PG   = (float*)(ws + 67108864ull);       // 64 MB: P (fp32) / G; resnet: xTsB
  u16*   xTsB = (u16*)  (ws + 67108864ull);       // 33.6 MB (resnet phase, conv1 output)
  u16*   Sf   = (u16*)  (ws + 134217728ull);      // 32 MB hi/lo swizzled fwd states
  u16*   Sb   = (u16*)  (ws + 167772160ull);      // 32 MB bwd states
  u16*   xTsA = (u16*)  (ws + 134217728ull);      // 33.6 MB (resnet + dec phases, aliases Sf/Sb)
  u16*   A1c  = (u16*)  (ws + 201326592ull);      // 8 MB
  u16*   A2c  = (u16*)  (ws + 209715200ull);      // 16 MB
  u16*   wswz = (u16*)  (ws + 226492416ull);      // 1.35 MB
  u16*   wdec = (u16*)  (ws + 227868672ull);      // 60 KB
  float* dssp = (float*)(ws + 227930112ull);      // 384 KB
  float* rC   = (float*)(ws + 228323328ull);      // 32 KB
  u16*   wglu = (u16*)  (ws + 228356096ull);      // 512 KB

  k_xpad<<<16, 256, 0, stream>>>(xTsA);
  k_xpad<<<16, 256, 0, stream>>>(xTsB);
  k_wxform<<<2688, 256, 0, stream>>>(rn_w1, rn_w2, wswz);
  k_wdec<<<120, 256, 0, stream>>>(dec_w, wdec);
  k_wglu<<<512, 256, 0, stream>>>(out_w, wglu);
  k_dssprep<<<64, 256, 0, stream>>>(lam_re, lam_im, log_dt, W_re, W_im, dssp);
  k_enc<<<dim3(128, 16), 128, 0, stream>>>(x_in, enc_w, enc_b, X);
  k_xform<<<dim3(128, 16), 256, 0, stream>>>(X, xTsA);

  for (int r = 0; r < 3; ++r){
    k_conv<<<dim3(64, 16), 256, 0, stream>>>(xTsA, (const u16*)((char*)wswz + (size_t)(2 * r) * 229376),
        rn_g1 + r * HCH, rn_b1 + r * HCH, rn_be1 + r * HCH, nullptr, nullptr, xTsB);
    k_conv<<<dim3(64, 16), 256, 0, stream>>>(xTsB, (const u16*)((char*)wswz + (size_t)(2 * r + 1) * 229376),
        rn_g2 + r * HCH, rn_b2 + r * HCH, rn_be2 + r * HCH, X, X, (r == 2) ? nullptr : xTsA);
  }
  for (int dl = 0; dl < NLAY; ++dl){
    k_mats<<<128, 256, 0, stream>>>(dssp + (size_t)dl * 6 * HCH * NST, A1c, A2c, rC);
    k_dss1<<<dim3(128, 8), 256, 0, stream>>>(X, A1c, PG);
    k_scan<<<512, 256, 0, stream>>>(PG, rC, Sf, Sb);
    k_dss2<<<dim3(128, 8), 256, 0, stream>>>(X, A2c, Sf, Sb, Dv + dl * HCH, PG);
    k_glu2<<<dim3(128, 16), 256, 0, stream>>>(PG, (const u16*)((char*)wglu + (size_t)dl * 131072),
        out_b + dl * 256, ln_g + dl * HCH, ln_b + dl * HCH, X);
  }
  k_xpad<<<16, 256, 0, stream>>>(xTsA);
  k_xform<<<dim3(128, 16), 256, 0, stream>>>(X, xTsA);
  k_dec2<<<dim3(64, 16), 256, 0, stream>>>(xTsA, wdec, dec_b, (float*)d_out);
}